// Round 3
// baseline (564.668 us; speedup 1.0000x reference)
//
#include <hip/hip_runtime.h>
#include <hip/hip_bf16.h>

typedef unsigned short u16;
typedef unsigned int u32;
typedef short bf16x8 __attribute__((ext_vector_type(8)));
typedef float floatx4 __attribute__((ext_vector_type(4)));

#define CTX 2048
#define HEADSZ 64
#define NHEAD 16
#define DMODEL 1024
#define DFF 4096
#define MROWS 8192  // B*T
#define C_SCALE 0.18033688011112042f  // 0.125 * log2(e)

__device__ __forceinline__ u16 f2b(float f) {
  union { float f; u32 i; } x; x.f = f;
  u32 i = x.i;
  return (u16)((i + 0x7fffu + ((i >> 16) & 1u)) >> 16);  // RNE
}
__device__ __forceinline__ u32 pack2(float a, float b) {
  return (u32)f2b(a) | ((u32)f2b(b) << 16);
}
__device__ __forceinline__ u32 cvtpk(float a, float b) {
  u32 r;
  asm("v_cvt_pk_bf16_f32 %0, %1, %2" : "=v"(r) : "v"(a), "v"(b));
  return r;
}
__device__ __forceinline__ floatx4 fmax4(floatx4 a, floatx4 b) {
  floatx4 r;
  r[0] = fmaxf(a[0], b[0]); r[1] = fmaxf(a[1], b[1]);
  r[2] = fmaxf(a[2], b[2]); r[3] = fmaxf(a[3], b[3]);
  return r;
}

__device__ __forceinline__ void gl2lds16(const u16* g, u16* l) {
  __builtin_amdgcn_global_load_lds(
      (const __attribute__((address_space(1))) void*)g,
      (__attribute__((address_space(3))) void*)l, 16, 0, 0);
}

// ---------------- elementwise fp32 -> bf16 (4 elems/thread) -------------------
__global__ __launch_bounds__(256) void cvt_f32_bf16(const float* __restrict__ in,
                                                    u16* __restrict__ out) {
  int i = (blockIdx.x * 256 + threadIdx.x) * 4;
  float4 v = *(const float4*)(in + i);
  *(uint2*)(out + i) = make_uint2(pack2(v.x, v.y), pack2(v.z, v.w));
}

// ------------- batched transpose: out_bf16[z][c][r] = in_f32[z][r][c] ---------
__global__ void transpose_f32_bf16(const float* __restrict__ in, u16* __restrict__ out,
                                   int R, int C, long ibs, long obs) {
  __shared__ u16 tile[32][33];
  const float* ip = in + (size_t)blockIdx.z * ibs;
  u16* op = out + (size_t)blockIdx.z * obs;
  int c0 = blockIdx.x * 32, r0 = blockIdx.y * 32;
  int tx = threadIdx.x, ty = threadIdx.y;
#pragma unroll
  for (int i = 0; i < 32; i += 8)
    tile[ty + i][tx] = f2b(ip[(size_t)(r0 + ty + i) * C + (c0 + tx)]);
  __syncthreads();
#pragma unroll
  for (int i = 0; i < 32; i += 8)
    op[(size_t)(c0 + ty + i) * R + (r0 + tx)] = tile[tx][ty + i];
}

// ------ combined per-head transpose of Wq/Wk/Wv [16][1024][64] fp32
//        -> Wqkvt rows sec*1024 + head*64 .. ( [64][1024] per head, bf16 )
__global__ void transpose_qkv(const float* __restrict__ Wq, const float* __restrict__ Wk,
                              const float* __restrict__ Wv, u16* __restrict__ out) {
  __shared__ u16 tile[32][33];
  int z = blockIdx.z;               // 0..47
  int sec = z >> 4, hh = z & 15;
  const float* ip = (sec == 0 ? Wq : sec == 1 ? Wk : Wv) + (size_t)hh * 65536;
  u16* op = out + (size_t)(sec * 16 + hh) * 65536;
  int c0 = blockIdx.x * 32, r0 = blockIdx.y * 32;
  int tx = threadIdx.x, ty = threadIdx.y;
#pragma unroll
  for (int i = 0; i < 32; i += 8)
    tile[ty + i][tx] = f2b(ip[(size_t)(r0 + ty + i) * 64 + (c0 + tx)]);
  __syncthreads();
#pragma unroll
  for (int i = 0; i < 32; i += 8)
    op[(size_t)(c0 + ty + i) * 1024 + (r0 + tx)] = tile[tx][ty + i];
}

// ------------- bf16 transpose: v [BH][2048][64] -> vt [BH][64][2048] ----------
__global__ void transpose_v_bf16(const u16* __restrict__ in, u16* __restrict__ out) {
  __shared__ u16 tile[32][33];
  const u16* ip = in + (size_t)blockIdx.z * (CTX * 64);
  u16* op = out + (size_t)blockIdx.z * (CTX * 64);
  int c0 = blockIdx.x * 32, r0 = blockIdx.y * 32;
  int tx = threadIdx.x, ty = threadIdx.y;
#pragma unroll
  for (int i = 0; i < 32; i += 8)
    tile[ty + i][tx] = ip[(size_t)(r0 + ty + i) * 64 + (c0 + tx)];
  __syncthreads();
#pragma unroll
  for (int i = 0; i < 32; i += 8)
    op[(size_t)(c0 + ty + i) * CTX + (r0 + tx)] = tile[tx][ty + i];
}

// =============================================================================
// 256x256 8-phase GEMM (unchanged; see round-0 comments).
// =============================================================================
template <int MODE>
__global__ __launch_bounds__(512, 2) void gemm256(
    const u16* __restrict__ A, const u16* __restrict__ Bt,
    const float* __restrict__ bias,
    void* __restrict__ o0v, void* __restrict__ o1v, void* __restrict__ o2v,
    int N, int K) {
  __shared__ __align__(16) u16 As[2][16384];
  __shared__ __align__(16) u16 Bs[2][16384];
  const int tid = threadIdx.x;
  const int quad = (tid >> 4) & 3, l15 = tid & 15;
  const int wave = tid >> 6;
  const int wr = wave >> 2, wc = wave & 3;

  const int id = blockIdx.x;
  const int blockM = (((id & 7) << 2) | ((id >> 3) & 3)) << 8;
  const int blockN = (id >> 5) << 8;

  const int sub = tid >> 3;                    // 0..63
  const int kslot = (tid & 7) ^ (sub & 7);     // pre-swizzled global k-slot
  const int rA = blockM + ((sub >> 5) << 7) + (sub & 31);
  const u16* a0 = A + (size_t)(rA + 0) * K + kslot * 8;
  const u16* a1 = A + (size_t)(rA + 32) * K + kslot * 8;
  const u16* a2 = A + (size_t)(rA + 64) * K + kslot * 8;
  const u16* a3 = A + (size_t)(rA + 96) * K + kslot * 8;
  const int rB = blockN + sub;
  const u16* b0 = Bt + (size_t)(rB + 0) * K + kslot * 8;
  const u16* b1 = Bt + (size_t)(rB + 64) * K + kslot * 8;
  const u16* b2 = Bt + (size_t)(rB + 128) * K + kslot * 8;
  const u16* b3 = Bt + (size_t)(rB + 192) * K + kslot * 8;

  const int arow = ((wr << 5) + l15) << 7;
  const int brow = ((wc << 6) + l15) << 7;
  const int swz0 = (quad ^ (l15 & 7)) << 4;
  const int swz1 = ((4 + quad) ^ (l15 & 7)) << 4;

  floatx4 acc[8][4];
#pragma unroll
  for (int i = 0; i < 8; i++)
#pragma unroll
    for (int j = 0; j < 4; j++) acc[i][j] = (floatx4){0.f, 0.f, 0.f, 0.f};

  const int nk = K >> 6;

  gl2lds16(a0, &As[0][0 * 4096 + tid * 8]);
  gl2lds16(a1, &As[0][1 * 4096 + tid * 8]);
  gl2lds16(a2, &As[0][2 * 4096 + tid * 8]);
  gl2lds16(a3, &As[0][3 * 4096 + tid * 8]);
  gl2lds16(b0, &Bs[0][0 * 4096 + tid * 8]);
  gl2lds16(b1, &Bs[0][1 * 4096 + tid * 8]);
  gl2lds16(b2, &Bs[0][2 * 4096 + tid * 8]);
  gl2lds16(b3, &Bs[0][3 * 4096 + tid * 8]);
  gl2lds16(b0 + 64, &Bs[1][0 * 4096 + tid * 8]);
  gl2lds16(b1 + 64, &Bs[1][1 * 4096 + tid * 8]);
  gl2lds16(b2 + 64, &Bs[1][2 * 4096 + tid * 8]);
  gl2lds16(b3 + 64, &Bs[1][3 * 4096 + tid * 8]);
  gl2lds16(a0 + 64, &As[1][0 * 4096 + tid * 8]);
  gl2lds16(a1 + 64, &As[1][1 * 4096 + tid * 8]);
  asm volatile("s_waitcnt vmcnt(6)" ::: "memory");
  __builtin_amdgcn_s_barrier();
  a0 += 128; a1 += 128; a2 += 64; a3 += 64;
  b0 += 128; b1 += 128; b2 += 128; b3 += 128;

#define LOAD_AR(q)                                                             \
  _Pragma("unroll") for (int mm = 0; mm < 2; mm++) {                           \
    ar[mm][0] = *(const bf16x8*)(ab + (q) * 8192 + mm * 2048 + arow + swz0);   \
    ar[mm][1] = *(const bf16x8*)(ab + (q) * 8192 + mm * 2048 + arow + swz1);   \
  }
#define MFMA_PH(q)                                                             \
  __builtin_amdgcn_s_setprio(1);                                               \
  _Pragma("unroll") for (int mm = 0; mm < 2; mm++)                             \
  _Pragma("unroll") for (int nf = 0; nf < 4; nf++)                             \
    acc[(q) * 2 + mm][nf] = __builtin_amdgcn_mfma_f32_16x16x32_bf16(           \
        ar[mm][0], br[nf][0], acc[(q) * 2 + mm][nf], 0, 0, 0);                 \
  _Pragma("unroll") for (int mm = 0; mm < 2; mm++)                             \
  _Pragma("unroll") for (int nf = 0; nf < 4; nf++)                             \
    acc[(q) * 2 + mm][nf] = __builtin_amdgcn_mfma_f32_16x16x32_bf16(           \
        ar[mm][1], br[nf][1], acc[(q) * 2 + mm][nf], 0, 0, 0);                 \
  __builtin_amdgcn_s_setprio(0);

#pragma unroll 1
  for (int t = 0; t < nk; t++) {
    const char* ab = (const char*)As[t & 1];
    const char* bb = (const char*)Bs[t & 1];
    u16* An = As[(t + 1) & 1];
    u16* Ac = As[t & 1];
    u16* Bc = Bs[t & 1];
    const bool st1 = (t + 1 < nk), st2 = (t + 2 < nk);
    bf16x8 br[4][2], ar[2][2];

#pragma unroll
    for (int nf = 0; nf < 4; nf++) {
      br[nf][0] = *(const bf16x8*)(bb + nf * 2048 + brow + swz0);
      br[nf][1] = *(const bf16x8*)(bb + nf * 2048 + brow + swz1);
    }
    LOAD_AR(0)
    if (st1) {
      gl2lds16(a2, An + 2 * 4096 + tid * 8);
      gl2lds16(a3, An + 3 * 4096 + tid * 8);
    }
    __builtin_amdgcn_s_barrier();
    asm volatile("s_waitcnt lgkmcnt(0)" ::: "memory");
    MFMA_PH(0)
    __builtin_amdgcn_s_barrier();

    LOAD_AR(1)
    if (st2) {
      gl2lds16(b0, Bc + 0 * 4096 + tid * 8);
      gl2lds16(b1, Bc + 1 * 4096 + tid * 8);
    }
    __builtin_amdgcn_s_barrier();
    asm volatile("s_waitcnt lgkmcnt(0)" ::: "memory");
    MFMA_PH(1)
    __builtin_amdgcn_s_barrier();

    LOAD_AR(2)
    if (st2) {
      gl2lds16(b2, Bc + 2 * 4096 + tid * 8);
      gl2lds16(b3, Bc + 3 * 4096 + tid * 8);
    }
    __builtin_amdgcn_s_barrier();
    asm volatile("s_waitcnt lgkmcnt(0)" ::: "memory");
    MFMA_PH(2)
    __builtin_amdgcn_s_barrier();

    LOAD_AR(3)
    if (st2) {
      gl2lds16(a0, Ac + 0 * 4096 + tid * 8);
      gl2lds16(a1, Ac + 1 * 4096 + tid * 8);
    }
    __builtin_amdgcn_s_barrier();
    asm volatile("s_waitcnt lgkmcnt(0)" ::: "memory");
    MFMA_PH(3)
    if (st2)
      asm volatile("s_waitcnt vmcnt(6)" ::: "memory");
    else
      asm volatile("s_waitcnt vmcnt(0)" ::: "memory");
    __builtin_amdgcn_s_barrier();

    a0 += 64; a1 += 64; a2 += 64; a3 += 64;
    b0 += 64; b1 += 64; b2 += 64; b3 += 64;
  }
#undef LOAD_AR
#undef MFMA_PH

  const int m0 = blockM + wr * 128 + quad * 4;
  const int n0 = blockN + wc * 64 + l15;
  if (MODE == 0) {
    u16* o0 = (u16*)o0v; u16* o1 = (u16*)o1v; u16* o2 = (u16*)o2v;
#pragma unroll
    for (int nf = 0; nf < 4; nf++) {
      int n = n0 + nf * 16;
      int sec = n >> 10, hh = (n >> 6) & 15, d = n & 63;
      u16* dst = (sec == 0) ? o0 : (sec == 1) ? o1 : o2;
#pragma unroll
      for (int mf = 0; mf < 8; mf++)
#pragma unroll
        for (int r = 0; r < 4; r++) {
          int m = m0 + mf * 16 + r;
          int b = m >> 11, tt = m & 2047;
          dst[((size_t)((b * 16 + hh) * 2048 + tt)) * 64 + d] = f2b(acc[mf][nf][r]);
        }
    }
  } else if (MODE == 1) {
    u16* o0 = (u16*)o0v;
#pragma unroll
    for (int nf = 0; nf < 4; nf++) {
      int n = n0 + nf * 16;
      float bv = bias[n];
#pragma unroll
      for (int mf = 0; mf < 8; mf++)
#pragma unroll
        for (int r = 0; r < 4; r++) {
          int m = m0 + mf * 16 + r;
          o0[(size_t)m * N + n] = f2b(acc[mf][nf][r] + bv);
        }
    }
  } else {
    float* o0 = (float*)o0v;
#pragma unroll
    for (int nf = 0; nf < 4; nf++) {
      int n = n0 + nf * 16;
      float bv = bias[n];
#pragma unroll
      for (int mf = 0; mf < 8; mf++)
#pragma unroll
        for (int r = 0; r < 4; r++) {
          int m = m0 + mf * 16 + r;
          float v = acc[mf][nf][r] + bv;
          o0[(size_t)m * N + n] = v > 0.f ? v : 0.f;
        }
    }
  }
}

// =============================================================================
// 128x256 8-phase GEMM for FFN2 (unchanged; see round-1 comments).
// =============================================================================
__global__ __launch_bounds__(512, 2) void gemm128(
    const u16* __restrict__ A, const u16* __restrict__ Bt,
    const float* __restrict__ bias, float* __restrict__ out,
    int N, int K) {
  __shared__ __align__(16) u16 As[2][8192];
  __shared__ __align__(16) u16 Bs[2][16384];
  const int tid = threadIdx.x;
  const int quad = (tid >> 4) & 3, l15 = tid & 15;
  const int wave = tid >> 6;
  const int wr = wave >> 2, wc = wave & 3;

  const int id = blockIdx.x;
  const int blockM = (((id & 7) << 3) | ((id >> 3) & 7)) << 7;  // 64 M-tiles
  const int blockN = (id >> 6) << 8;                            // 4 N-tiles

  const int sub = tid >> 3;
  const int kslot = (tid & 7) ^ (sub & 7);
  const int rA = blockM + ((sub >> 5) << 6) + (sub & 31);
  const u16* a0 = A + (size_t)(rA + 0) * K + kslot * 8;
  const u16* a1 = A + (size_t)(rA + 32) * K + kslot * 8;
  const int rB = blockN + sub;
  const u16* b0 = Bt + (size_t)(rB + 0) * K + kslot * 8;
  const u16* b1 = Bt + (size_t)(rB + 64) * K + kslot * 8;
  const u16* b2 = Bt + (size_t)(rB + 128) * K + kslot * 8;
  const u16* b3 = Bt + (size_t)(rB + 192) * K + kslot * 8;

  const int arow = ((wr << 5) + l15) << 7;
  const int brow = ((wc << 6) + l15) << 7;
  const int swz0 = (quad ^ (l15 & 7)) << 4;
  const int swz1 = ((4 + quad) ^ (l15 & 7)) << 4;

  floatx4 acc[4][4];
#pragma unroll
  for (int i = 0; i < 4; i++)
#pragma unroll
    for (int j = 0; j < 4; j++) acc[i][j] = (floatx4){0.f, 0.f, 0.f, 0.f};

  const int nk = K >> 6;

  gl2lds16(a0, &As[0][tid * 8]);
  gl2lds16(a1, &As[0][4096 + tid * 8]);
  gl2lds16(b0, &Bs[0][0 * 4096 + tid * 8]);
  gl2lds16(b1, &Bs[0][1 * 4096 + tid * 8]);
  gl2lds16(b2, &Bs[0][2 * 4096 + tid * 8]);
  gl2lds16(b3, &Bs[0][3 * 4096 + tid * 8]);
  gl2lds16(b0 + 64, &Bs[1][0 * 4096 + tid * 8]);
  gl2lds16(b1 + 64, &Bs[1][1 * 4096 + tid * 8]);
  gl2lds16(b2 + 64, &Bs[1][2 * 4096 + tid * 8]);
  gl2lds16(b3 + 64, &Bs[1][3 * 4096 + tid * 8]);
  gl2lds16(a0 + 64, &As[1][tid * 8]);
  asm volatile("s_waitcnt vmcnt(5)" ::: "memory");
  __builtin_amdgcn_s_barrier();
  a0 += 128; a1 += 64;
  b0 += 128; b1 += 128; b2 += 128; b3 += 128;

#define LOAD_AR1(q)                                                            \
  ar[0] = *(const bf16x8*)(ab + ((q) >> 1) * 8192 + ((q) & 1) * 2048 + arow + swz0); \
  ar[1] = *(const bf16x8*)(ab + ((q) >> 1) * 8192 + ((q) & 1) * 2048 + arow + swz1);
#define MFMA_PH1(q)                                                            \
  __builtin_amdgcn_s_setprio(1);                                               \
  _Pragma("unroll") for (int nf = 0; nf < 4; nf++)                             \
    acc[q][nf] = __builtin_amdgcn_mfma_f32_16x16x32_bf16(                      \
        ar[0], br[nf][0], acc[q][nf], 0, 0, 0);                                \
  _Pragma("unroll") for (int nf = 0; nf < 4; nf++)                             \
    acc[q][nf] = __builtin_amdgcn_mfma_f32_16x16x32_bf16(                      \
        ar[1], br[nf][1], acc[q][nf], 0, 0, 0);                                \
  __builtin_amdgcn_s_setprio(0);

#pragma unroll 1
  for (int t = 0; t < nk; t++) {
    const char* ab = (const char*)As[t & 1];
    const char* bb = (const char*)Bs[t & 1];
    u16* An = As[(t + 1) & 1];
    u16* Ac = As[t & 1];
    u16* Bc = Bs[t & 1];
    const bool st1 = (t + 1 < nk), st2 = (t + 2 < nk);
    bf16x8 br[4][2], ar[2];

#pragma unroll
    for (int nf = 0; nf < 4; nf++) {
      br[nf][0] = *(const bf16x8*)(bb + nf * 2048 + brow + swz0);
      br[nf][1] = *(const bf16x8*)(bb + nf * 2048 + brow + swz1);
    }
    LOAD_AR1(0)
    if (st1) gl2lds16(a1, An + 4096 + tid * 8);
    __builtin_amdgcn_s_barrier();
    asm volatile("s_waitcnt lgkmcnt(0)" ::: "memory");
    MFMA_PH1(0)
    __builtin_amdgcn_s_barrier();

    LOAD_AR1(1)
    if (st2) {
      gl2lds16(b0, Bc + 0 * 4096 + tid * 8);
      gl2lds16(b1, Bc + 1 * 4096 + tid * 8);
    }
    __builtin_amdgcn_s_barrier();
    asm volatile("s_waitcnt lgkmcnt(0)" ::: "memory");
    MFMA_PH1(1)
    __builtin_amdgcn_s_barrier();

    LOAD_AR1(2)
    if (st2) {
      gl2lds16(b2, Bc + 2 * 4096 + tid * 8);
      gl2lds16(b3, Bc + 3 * 4096 + tid * 8);
    }
    __builtin_amdgcn_s_barrier();
    asm volatile("s_waitcnt lgkmcnt(0)" ::: "memory");
    MFMA_PH1(2)
    __builtin_amdgcn_s_barrier();

    LOAD_AR1(3)
    if (st2) gl2lds16(a0, Ac + tid * 8);
    __builtin_amdgcn_s_barrier();
    asm volatile("s_waitcnt lgkmcnt(0)" ::: "memory");
    MFMA_PH1(3)
    if (st2)
      asm volatile("s_waitcnt vmcnt(6)" ::: "memory");
    else
      asm volatile("s_waitcnt vmcnt(0)" ::: "memory");
    __builtin_amdgcn_s_barrier();

    a0 += 64; a1 += 64;
    b0 += 64; b1 += 64; b2 += 64; b3 += 64;
  }
#undef LOAD_AR1
#undef MFMA_PH1

  const int m0 = blockM + wr * 64 + quad * 4;
  const int n0 = blockN + wc * 64 + l15;
#pragma unroll
  for (int nf = 0; nf < 4; nf++) {
    int n = n0 + nf * 16;
    float bv = bias[n];
#pragma unroll
    for (int mf = 0; mf < 4; mf++)
#pragma unroll
      for (int r = 0; r < 4; r++) {
        int m = m0 + mf * 16 + r;
        float v = acc[mf][nf][r] + bv;
        out[(size_t)m * N + n] = v > 0.f ? v : 0.f;
      }
  }
}

// =============================================================================
// Barrier-free MFMA causal flash attention, direct-L2 K/V streaming.
// K/V per head = 512 KB -> L2-resident; LDS staging dropped entirely.
// 128 threads = 2 independent waves, wave w owns q-rows [ (2t+w)*32, +32 ).
// Both waves have IDENTICAL stage counts (t+1) -> balanced blocks; grid 2048,
// longest blocks (t=31) dispatched first. XCD swizzle: bh % 8 == id % 8 pins
// each bh-class to one XCD (8 bh x 512 KB = 4 MB = one L2).
// Zero-extra-reg software pipeline: K(st+1) regs issued right after QK(st)
// consumes them (lands under softmax+PV); V(st+1) issued after PV(st)
// (lands under next QK+softmax). Plds is per-wave (lgkm-only sync).
// =============================================================================
__global__ __launch_bounds__(128, 3) void attn_mfma(
    const u16* __restrict__ Q, const u16* __restrict__ K,
    const u16* __restrict__ Vt, u16* __restrict__ out) {
  __shared__ __align__(16) u16 Plds[2][32][72];
  const int tid = threadIdx.x;
  const int wave = tid >> 6, lane = tid & 63;
  const int quad = lane >> 4, l15 = lane & 15;

  const int id = blockIdx.x;
  const int r = id >> 3;
  const int bh = (id & 7) + ((r & 7) << 3);   // bh % 8 == XCD slot
  const int t = 31 - (r >> 3);                // 31..0, longest first
  const int j32 = 2 * t + wave;               // wave-pair: equal NST
  const int qbase = j32 << 5;
  const int NST = (j32 >> 1) + 1;
  const size_t qkb = (size_t)bh * (CTX * 64);
  const size_t vbb = (size_t)bh * (64 * CTX);

  const u16* kb_ = K + qkb + (size_t)l15 * 64 + quad * 8;
  const u16* vb_ = Vt + vbb + (size_t)l15 * CTX + quad * 8;

  bf16x8 qf[2][2];
#pragma unroll
  for (int mt = 0; mt < 2; mt++)
#pragma unroll
    for (int kc = 0; kc < 2; kc++)
      qf[mt][kc] = *(const bf16x8*)(Q + qkb + (size_t)(qbase + mt * 16 + l15) * 64 + kc * 32 + quad * 8);

  floatx4 o[2][4];
#pragma unroll
  for (int mt = 0; mt < 2; mt++)
#pragma unroll
    for (int dt = 0; dt < 4; dt++) o[mt][dt] = (floatx4){0.f, 0.f, 0.f, 0.f};
  float mrow[2] = {-1e30f, -1e30f};
  float lrow[2] = {0.f, 0.f};

  // preload stage 0 K/V fragments into registers
  bf16x8 kr[4][2], vr[2][4];
#pragma unroll
  for (int sc = 0; sc < 4; sc++) {
    kr[sc][0] = *(const bf16x8*)(kb_ + (size_t)(sc * 16) * 64);
    kr[sc][1] = *(const bf16x8*)(kb_ + (size_t)(sc * 16) * 64 + 32);
  }
#pragma unroll
  for (int sc2 = 0; sc2 < 2; sc2++)
#pragma unroll
    for (int dt = 0; dt < 4; dt++)
      vr[sc2][dt] = *(const bf16x8*)(vb_ + (size_t)(dt * 16) * CTX + sc2 * 32);

#pragma unroll 1
  for (int st = 0; st < NST; st++) {
    const int sbase = st << 6;
    const int sbn = (st + 1 < NST) ? (st + 1) << 6 : 0;  // harmless reload at end
    const bool last = (st == NST - 1);

#pragma unroll
    for (int mt = 0; mt < 2; mt++) {
      floatx4 stf[4];
      __builtin_amdgcn_s_setprio(1);
#pragma unroll
      for (int sc = 0; sc < 4; sc++) {
        floatx4 z = (floatx4){0.f, 0.f, 0.f, 0.f};
        z = __builtin_amdgcn_mfma_f32_16x16x32_bf16(kr[sc][0], qf[mt][0], z, 0, 0, 0);
        stf[sc] = __builtin_amdgcn_mfma_f32_16x16x32_bf16(kr[sc][1], qf[mt][1], z, 0, 0, 0);
      }
      __builtin_amdgcn_s_setprio(0);
      if (mt == 1) {
        // kr dead: issue K(st+1) loads; land during PV + next-stage softmax
#pragma unroll
        for (int sc = 0; sc < 4; sc++) {
          kr[sc][0] = *(const bf16x8*)(kb_ + (size_t)(sbn + sc * 16) * 64);
          kr[sc][1] = *(const bf16x8*)(kb_ + (size_t)(sbn + sc * 16) * 64 + 32);
        }
      }
      if (last) {
        int qq = qbase + mt * 16 + l15;
#pragma unroll
        for (int sc = 0; sc < 4; sc++)
#pragma unroll
          for (int rr = 0; rr < 4; rr++) {
            int s = sbase + sc * 16 + quad * 4 + rr;
            if (s > qq) stf[sc][rr] = -1e30f;
          }
      }
      floatx4 m4 = fmax4(fmax4(stf[0], stf[1]), fmax4(stf[2], stf[3]));
      float tm = fmaxf(fmaxf(m4[0], m4[1]), fmaxf(m4[2], m4[3]));
      tm = fmaxf(tm, __shfl_xor(tm, 16));
      tm = fmaxf(tm, __shfl_xor(tm, 32));
      // T13 defer-max
      if (!__all(tm <= mrow[mt] + 8.0f)) {
        float mnew = fmaxf(mrow[mt], tm);
        float alpha = exp2f((mrow[mt] - mnew) * C_SCALE);
        mrow[mt] = mnew;
        lrow[mt] *= alpha;
#pragma unroll
        for (int dt = 0; dt < 4; dt++) o[mt][dt] *= alpha;
      }
      const float mneg = -mrow[mt] * C_SCALE;
      float lsum = 0.f;
#pragma unroll
      for (int sc = 0; sc < 4; sc++) {
        floatx4 s4 = stf[sc];
        float p0 = exp2f(fmaf(s4[0], C_SCALE, mneg));
        float p1 = exp2f(fmaf(s4[1], C_SCALE, mneg));
        float p2 = exp2f(fmaf(s4[2], C_SCALE, mneg));
        float p3 = exp2f(fmaf(s4[3], C_SCALE, mneg));
        lsum += (p0 + p1) + (p2 + p3);
        *(uint2*)&Plds[wave][mt * 16 + l15][sc * 16 + quad * 4] =
            make_uint2(cvtpk(p0, p1), cvtpk(p2, p3));
      }
      lrow[mt] += lsum;
    }
    asm volatile("s_waitcnt lgkmcnt(0)" ::: "memory");
#pragma unroll
    for (int sc2 = 0; sc2 < 2; sc2++) {
      bf16x8 pf[2];
#pragma unroll
      for (int mt = 0; mt < 2; mt++)
        pf[mt] = *(const bf16x8*)&Plds[wave][mt * 16 + l15][sc2 * 32 + quad * 8];
      __builtin_amdgcn_s_setprio(1);
#pragma unroll
      for (int dt = 0; dt < 4; dt++)
#pragma unroll
        for (int mt = 0; mt < 2; mt++)
          o[mt][dt] = __builtin_amdgcn_mfma_f32_16x16x32_bf16(vr[sc2][dt], pf[mt], o[mt][dt], 0, 0, 0);
      __builtin_amdgcn_s_setprio(0);
    }
    // vr dead: issue V(st+1) loads; land during next QK + softmax
#pragma unroll
    for (int sc2 = 0; sc2 < 2; sc2++)
#pragma unroll
      for (int dt = 0; dt < 4; dt++)
        vr[sc2][dt] = *(const bf16x8*)(vb_ + (size_t)(dt * 16) * CTX + sbn + sc2 * 32);
  }

#pragma unroll
  for (int mt = 0; mt < 2; mt++) {
    float l = lrow[mt];
    l += __shfl_xor(l, 16);
    l += __shfl_xor(l, 32);
    float inv = 1.0f / l;
    int row = (bh >> 4) * CTX + qbase + mt * 16 + l15;
    u16* orow = out + (size_t)row * DMODEL + (bh & 15) * 64;
#pragma unroll
    for (int dt = 0; dt < 4; dt++) {
      floatx4 v = o[mt][dt];
      *(u32*)(orow + dt * 16 + quad * 4) = cvtpk(v[0] * inv, v[1] * inv);
      *(u32*)(orow + dt * 16 + quad * 4 + 2) = cvtpk(v[2] * inv, v[3] * inv);
    }
  }
}

extern "C" void kernel_launch(void* const* d_in, const int* in_sizes, int n_in,
                              void* d_out, int out_size, void* d_ws, size_t ws_size,
                              hipStream_t stream) {
  const float* x  = (const float*)d_in[0];
  const float* Wq = (const float*)d_in[1];
  const float* Wk = (const float*)d_in[2];
  const float* Wv = (const float*)d_in[3];
  const float* W1 = (const float*)d_in[4];
  const float* b1 = (const float*)d_in[5];
  const float* W2 = (const float*)d_in[6];
  const float* b2 = (const float*)d_in[7];
  float* out = (float*)d_out;

  u16* ws    = (u16*)d_ws;
  u16* W1t   = ws;                             // [4096][1024]
  u16* W2t   = W1t + (size_t)4096 * 1024;      // [1024][4096]
  u16* att   = W2t + (size_t)4096 * 1024;      // [B*T][1024]  (also v_tmp)
  u16* xb    = att + (size_t)MROWS * 1024;     // [B*T][1024]
  u16* Wqkvt = xb + (size_t)MROWS * 1024;      // [3072][1024]
  u16* q     = Wqkvt + (size_t)3072 * 1024;    // [B*H][T][64]
  u16* k     = q + (size_t)MROWS * 1024;       // [B*H][T][64]
  u16* vt    = k + (size_t)MROWS * 1024;       // [B*H][64][T]
  u16* v_tmp = att;                            // [B*H][T][64]
  u16* h     = xb;                             // [B*T][4096] overlaps xb..vt

  cvt_f32_bf16<<<MROWS * 1024 / 1024, 256, 0, stream>>>(x, xb);

  dim3 tb(32, 8);
  transpose_qkv<<<dim3(2, 32, 48), tb, 0, stream>>>(Wq, Wk, Wv, Wqkvt);
  transpose_f32_bf16<<<dim3(128, 32, 1), tb, 0, stream>>>(W1, W1t, 1024, 4096, 0, 0);
  transpose_f32_bf16<<<dim3(32, 128, 1), tb, 0, stream>>>(W2, W2t, 4096, 1024, 0, 0);

  // QKV projection: [8192][1024] x [3072][1024]^T -> q/k/v (coalesced scatter)
  gemm256<0><<<384, 512, 0, stream>>>(xb, Wqkvt, nullptr, q, k, v_tmp, 3072, 1024);
  // v [BH][T][64] -> vt [BH][64][T]
  transpose_v_bf16<<<dim3(2, 64, 64), tb, 0, stream>>>(v_tmp, vt);
  // Barrier-free MFMA causal flash attention -> att [B*T][1024]
  attn_mfma<<<2048, 128, 0, stream>>>(q, k, vt, att);
  // FFN1: att @ W1 + b1 -> h (bf16)
  gemm256<1><<<512, 512, 0, stream>>>(att, W1t, b1, h, nullptr, nullptr, 4096, 1024);
  // FFN2: relu(h @ W2 + b2) -> out (fp32), 128x256 tiles = 256 wg (full chip)
  gemm128<<<256, 512, 0, stream>>>(h, W2t, b2, out, 1024, 4096);
}

// Round 4
// 466.620 us; speedup vs baseline: 1.2101x; 1.2101x over previous
//
#include <hip/hip_runtime.h>
#include <hip/hip_bf16.h>

typedef unsigned short u16;
typedef unsigned int u32;
typedef short bf16x8 __attribute__((ext_vector_type(8)));
typedef float floatx4 __attribute__((ext_vector_type(4)));

#define CTX 2048
#define HEADSZ 64
#define NHEAD 16
#define DMODEL 1024
#define DFF 4096
#define MROWS 8192  // B*T
#define C_SCALE 0.18033688011112042f  // 0.125 * log2(e)

__device__ __forceinline__ u16 f2b(float f) {
  union { float f; u32 i; } x; x.f = f;
  u32 i = x.i;
  return (u16)((i + 0x7fffu + ((i >> 16) & 1u)) >> 16);  // RNE
}
__device__ __forceinline__ u32 pack2(float a, float b) {
  return (u32)f2b(a) | ((u32)f2b(b) << 16);
}
__device__ __forceinline__ u32 cvtpk(float a, float b) {
  u32 r;
  asm("v_cvt_pk_bf16_f32 %0, %1, %2" : "=v"(r) : "v"(a), "v"(b));
  return r;
}
__device__ __forceinline__ floatx4 fmax4(floatx4 a, floatx4 b) {
  floatx4 r;
  r[0] = fmaxf(a[0], b[0]); r[1] = fmaxf(a[1], b[1]);
  r[2] = fmaxf(a[2], b[2]); r[3] = fmaxf(a[3], b[3]);
  return r;
}

__device__ __forceinline__ void gl2lds16(const u16* g, u16* l) {
  __builtin_amdgcn_global_load_lds(
      (const __attribute__((address_space(1))) void*)g,
      (__attribute__((address_space(3))) void*)l, 16, 0, 0);
}

// ---------------- elementwise fp32 -> bf16 (4 elems/thread) -------------------
__global__ __launch_bounds__(256) void cvt_f32_bf16(const float* __restrict__ in,
                                                    u16* __restrict__ out) {
  int i = (blockIdx.x * 256 + threadIdx.x) * 4;
  float4 v = *(const float4*)(in + i);
  *(uint2*)(out + i) = make_uint2(pack2(v.x, v.y), pack2(v.z, v.w));
}

// ------------- batched transpose: out_bf16[z][c][r] = in_f32[z][r][c] ---------
__global__ void transpose_f32_bf16(const float* __restrict__ in, u16* __restrict__ out,
                                   int R, int C, long ibs, long obs) {
  __shared__ u16 tile[32][33];
  const float* ip = in + (size_t)blockIdx.z * ibs;
  u16* op = out + (size_t)blockIdx.z * obs;
  int c0 = blockIdx.x * 32, r0 = blockIdx.y * 32;
  int tx = threadIdx.x, ty = threadIdx.y;
#pragma unroll
  for (int i = 0; i < 32; i += 8)
    tile[ty + i][tx] = f2b(ip[(size_t)(r0 + ty + i) * C + (c0 + tx)]);
  __syncthreads();
#pragma unroll
  for (int i = 0; i < 32; i += 8)
    op[(size_t)(c0 + ty + i) * R + (r0 + tx)] = tile[tx][ty + i];
}

// ------ combined per-head transpose of Wq/Wk/Wv [16][1024][64] fp32
//        -> Wqkvt rows sec*1024 + head*64 .. ( [64][1024] per head, bf16 )
__global__ void transpose_qkv(const float* __restrict__ Wq, const float* __restrict__ Wk,
                              const float* __restrict__ Wv, u16* __restrict__ out) {
  __shared__ u16 tile[32][33];
  int z = blockIdx.z;               // 0..47
  int sec = z >> 4, hh = z & 15;
  const float* ip = (sec == 0 ? Wq : sec == 1 ? Wk : Wv) + (size_t)hh * 65536;
  u16* op = out + (size_t)(sec * 16 + hh) * 65536;
  int c0 = blockIdx.x * 32, r0 = blockIdx.y * 32;
  int tx = threadIdx.x, ty = threadIdx.y;
#pragma unroll
  for (int i = 0; i < 32; i += 8)
    tile[ty + i][tx] = f2b(ip[(size_t)(r0 + ty + i) * 64 + (c0 + tx)]);
  __syncthreads();
#pragma unroll
  for (int i = 0; i < 32; i += 8)
    op[(size_t)(c0 + ty + i) * 1024 + (r0 + tx)] = tile[tx][ty + i];
}

// ------------- bf16 transpose: v [BH][2048][64] -> vt [BH][64][2048] ----------
__global__ void transpose_v_bf16(const u16* __restrict__ in, u16* __restrict__ out) {
  __shared__ u16 tile[32][33];
  const u16* ip = in + (size_t)blockIdx.z * (CTX * 64);
  u16* op = out + (size_t)blockIdx.z * (CTX * 64);
  int c0 = blockIdx.x * 32, r0 = blockIdx.y * 32;
  int tx = threadIdx.x, ty = threadIdx.y;
#pragma unroll
  for (int i = 0; i < 32; i += 8)
    tile[ty + i][tx] = ip[(size_t)(r0 + ty + i) * 64 + (c0 + tx)];
  __syncthreads();
#pragma unroll
  for (int i = 0; i < 32; i += 8)
    op[(size_t)(c0 + ty + i) * CTX + (r0 + tx)] = tile[tx][ty + i];
}

// =============================================================================
// 256x256 8-phase GEMM (unchanged; see round-0 comments).
// =============================================================================
template <int MODE>
__global__ __launch_bounds__(512, 2) void gemm256(
    const u16* __restrict__ A, const u16* __restrict__ Bt,
    const float* __restrict__ bias,
    void* __restrict__ o0v, void* __restrict__ o1v, void* __restrict__ o2v,
    int N, int K) {
  __shared__ __align__(16) u16 As[2][16384];
  __shared__ __align__(16) u16 Bs[2][16384];
  const int tid = threadIdx.x;
  const int quad = (tid >> 4) & 3, l15 = tid & 15;
  const int wave = tid >> 6;
  const int wr = wave >> 2, wc = wave & 3;

  const int id = blockIdx.x;
  const int blockM = (((id & 7) << 2) | ((id >> 3) & 3)) << 8;
  const int blockN = (id >> 5) << 8;

  const int sub = tid >> 3;                    // 0..63
  const int kslot = (tid & 7) ^ (sub & 7);     // pre-swizzled global k-slot
  const int rA = blockM + ((sub >> 5) << 7) + (sub & 31);
  const u16* a0 = A + (size_t)(rA + 0) * K + kslot * 8;
  const u16* a1 = A + (size_t)(rA + 32) * K + kslot * 8;
  const u16* a2 = A + (size_t)(rA + 64) * K + kslot * 8;
  const u16* a3 = A + (size_t)(rA + 96) * K + kslot * 8;
  const int rB = blockN + sub;
  const u16* b0 = Bt + (size_t)(rB + 0) * K + kslot * 8;
  const u16* b1 = Bt + (size_t)(rB + 64) * K + kslot * 8;
  const u16* b2 = Bt + (size_t)(rB + 128) * K + kslot * 8;
  const u16* b3 = Bt + (size_t)(rB + 192) * K + kslot * 8;

  const int arow = ((wr << 5) + l15) << 7;
  const int brow = ((wc << 6) + l15) << 7;
  const int swz0 = (quad ^ (l15 & 7)) << 4;
  const int swz1 = ((4 + quad) ^ (l15 & 7)) << 4;

  floatx4 acc[8][4];
#pragma unroll
  for (int i = 0; i < 8; i++)
#pragma unroll
    for (int j = 0; j < 4; j++) acc[i][j] = (floatx4){0.f, 0.f, 0.f, 0.f};

  const int nk = K >> 6;

  gl2lds16(a0, &As[0][0 * 4096 + tid * 8]);
  gl2lds16(a1, &As[0][1 * 4096 + tid * 8]);
  gl2lds16(a2, &As[0][2 * 4096 + tid * 8]);
  gl2lds16(a3, &As[0][3 * 4096 + tid * 8]);
  gl2lds16(b0, &Bs[0][0 * 4096 + tid * 8]);
  gl2lds16(b1, &Bs[0][1 * 4096 + tid * 8]);
  gl2lds16(b2, &Bs[0][2 * 4096 + tid * 8]);
  gl2lds16(b3, &Bs[0][3 * 4096 + tid * 8]);
  gl2lds16(b0 + 64, &Bs[1][0 * 4096 + tid * 8]);
  gl2lds16(b1 + 64, &Bs[1][1 * 4096 + tid * 8]);
  gl2lds16(b2 + 64, &Bs[1][2 * 4096 + tid * 8]);
  gl2lds16(b3 + 64, &Bs[1][3 * 4096 + tid * 8]);
  gl2lds16(a0 + 64, &As[1][0 * 4096 + tid * 8]);
  gl2lds16(a1 + 64, &As[1][1 * 4096 + tid * 8]);
  asm volatile("s_waitcnt vmcnt(6)" ::: "memory");
  __builtin_amdgcn_s_barrier();
  a0 += 128; a1 += 128; a2 += 64; a3 += 64;
  b0 += 128; b1 += 128; b2 += 128; b3 += 128;

#define LOAD_AR(q)                                                             \
  _Pragma("unroll") for (int mm = 0; mm < 2; mm++) {                           \
    ar[mm][0] = *(const bf16x8*)(ab + (q) * 8192 + mm * 2048 + arow + swz0);   \
    ar[mm][1] = *(const bf16x8*)(ab + (q) * 8192 + mm * 2048 + arow + swz1);   \
  }
#define MFMA_PH(q)                                                             \
  __builtin_amdgcn_s_setprio(1);                                               \
  _Pragma("unroll") for (int mm = 0; mm < 2; mm++)                             \
  _Pragma("unroll") for (int nf = 0; nf < 4; nf++)                             \
    acc[(q) * 2 + mm][nf] = __builtin_amdgcn_mfma_f32_16x16x32_bf16(           \
        ar[mm][0], br[nf][0], acc[(q) * 2 + mm][nf], 0, 0, 0);                 \
  _Pragma("unroll") for (int mm = 0; mm < 2; mm++)                             \
  _Pragma("unroll") for (int nf = 0; nf < 4; nf++)                             \
    acc[(q) * 2 + mm][nf] = __builtin_amdgcn_mfma_f32_16x16x32_bf16(           \
        ar[mm][1], br[nf][1], acc[(q) * 2 + mm][nf], 0, 0, 0);                 \
  __builtin_amdgcn_s_setprio(0);

#pragma unroll 1
  for (int t = 0; t < nk; t++) {
    const char* ab = (const char*)As[t & 1];
    const char* bb = (const char*)Bs[t & 1];
    u16* An = As[(t + 1) & 1];
    u16* Ac = As[t & 1];
    u16* Bc = Bs[t & 1];
    const bool st1 = (t + 1 < nk), st2 = (t + 2 < nk);
    bf16x8 br[4][2], ar[2][2];

#pragma unroll
    for (int nf = 0; nf < 4; nf++) {
      br[nf][0] = *(const bf16x8*)(bb + nf * 2048 + brow + swz0);
      br[nf][1] = *(const bf16x8*)(bb + nf * 2048 + brow + swz1);
    }
    LOAD_AR(0)
    if (st1) {
      gl2lds16(a2, An + 2 * 4096 + tid * 8);
      gl2lds16(a3, An + 3 * 4096 + tid * 8);
    }
    __builtin_amdgcn_s_barrier();
    asm volatile("s_waitcnt lgkmcnt(0)" ::: "memory");
    MFMA_PH(0)
    __builtin_amdgcn_s_barrier();

    LOAD_AR(1)
    if (st2) {
      gl2lds16(b0, Bc + 0 * 4096 + tid * 8);
      gl2lds16(b1, Bc + 1 * 4096 + tid * 8);
    }
    __builtin_amdgcn_s_barrier();
    asm volatile("s_waitcnt lgkmcnt(0)" ::: "memory");
    MFMA_PH(1)
    __builtin_amdgcn_s_barrier();

    LOAD_AR(2)
    if (st2) {
      gl2lds16(b2, Bc + 2 * 4096 + tid * 8);
      gl2lds16(b3, Bc + 3 * 4096 + tid * 8);
    }
    __builtin_amdgcn_s_barrier();
    asm volatile("s_waitcnt lgkmcnt(0)" ::: "memory");
    MFMA_PH(2)
    __builtin_amdgcn_s_barrier();

    LOAD_AR(3)
    if (st2) {
      gl2lds16(a0, Ac + 0 * 4096 + tid * 8);
      gl2lds16(a1, Ac + 1 * 4096 + tid * 8);
    }
    __builtin_amdgcn_s_barrier();
    asm volatile("s_waitcnt lgkmcnt(0)" ::: "memory");
    MFMA_PH(3)
    if (st2)
      asm volatile("s_waitcnt vmcnt(6)" ::: "memory");
    else
      asm volatile("s_waitcnt vmcnt(0)" ::: "memory");
    __builtin_amdgcn_s_barrier();

    a0 += 64; a1 += 64; a2 += 64; a3 += 64;
    b0 += 64; b1 += 64; b2 += 64; b3 += 64;
  }
#undef LOAD_AR
#undef MFMA_PH

  const int m0 = blockM + wr * 128 + quad * 4;
  const int n0 = blockN + wc * 64 + l15;
  if (MODE == 0) {
    u16* o0 = (u16*)o0v; u16* o1 = (u16*)o1v; u16* o2 = (u16*)o2v;
#pragma unroll
    for (int nf = 0; nf < 4; nf++) {
      int n = n0 + nf * 16;
      int sec = n >> 10, hh = (n >> 6) & 15, d = n & 63;
      u16* dst = (sec == 0) ? o0 : (sec == 1) ? o1 : o2;
#pragma unroll
      for (int mf = 0; mf < 8; mf++)
#pragma unroll
        for (int r = 0; r < 4; r++) {
          int m = m0 + mf * 16 + r;
          int b = m >> 11, tt = m & 2047;
          dst[((size_t)((b * 16 + hh) * 2048 + tt)) * 64 + d] = f2b(acc[mf][nf][r]);
        }
    }
  } else if (MODE == 1) {
    u16* o0 = (u16*)o0v;
#pragma unroll
    for (int nf = 0; nf < 4; nf++) {
      int n = n0 + nf * 16;
      float bv = bias[n];
#pragma unroll
      for (int mf = 0; mf < 8; mf++)
#pragma unroll
        for (int r = 0; r < 4; r++) {
          int m = m0 + mf * 16 + r;
          o0[(size_t)m * N + n] = f2b(acc[mf][nf][r] + bv);
        }
    }
  } else {
    float* o0 = (float*)o0v;
#pragma unroll
    for (int nf = 0; nf < 4; nf++) {
      int n = n0 + nf * 16;
      float bv = bias[n];
#pragma unroll
      for (int mf = 0; mf < 8; mf++)
#pragma unroll
        for (int r = 0; r < 4; r++) {
          int m = m0 + mf * 16 + r;
          float v = acc[mf][nf][r] + bv;
          o0[(size_t)m * N + n] = v > 0.f ? v : 0.f;
        }
    }
  }
}

// =============================================================================
// 128x256 8-phase GEMM, templatized epilogue:
//   MODE 0: scatter bf16 -> q/k/v [B,H,T,64]   (QKV: 64 Mtiles x 12 Ntiles
//           = 768 wg = 3 exact chip rounds; was 384 wg = 1.5 rounds at 256^2)
//   MODE 2: f32 relu(acc+bias)                 (FFN2: 256 wg = 1 round)
// Structure identical to round-1 gemm128 (verified on FFN2).
// =============================================================================
template <int MODE>
__global__ __launch_bounds__(512, 2) void gemm128(
    const u16* __restrict__ A, const u16* __restrict__ Bt,
    const float* __restrict__ bias,
    void* __restrict__ o0v, void* __restrict__ o1v, void* __restrict__ o2v,
    int N, int K) {
  __shared__ __align__(16) u16 As[2][8192];
  __shared__ __align__(16) u16 Bs[2][16384];
  const int tid = threadIdx.x;
  const int quad = (tid >> 4) & 3, l15 = tid & 15;
  const int wave = tid >> 6;
  const int wr = wave >> 2, wc = wave & 3;

  const int id = blockIdx.x;
  const int blockM = (((id & 7) << 3) | ((id >> 3) & 7)) << 7;  // 64 M-tiles
  const int blockN = (id >> 6) << 8;

  const int sub = tid >> 3;
  const int kslot = (tid & 7) ^ (sub & 7);
  const int rA = blockM + ((sub >> 5) << 6) + (sub & 31);
  const u16* a0 = A + (size_t)(rA + 0) * K + kslot * 8;
  const u16* a1 = A + (size_t)(rA + 32) * K + kslot * 8;
  const int rB = blockN + sub;
  const u16* b0 = Bt + (size_t)(rB + 0) * K + kslot * 8;
  const u16* b1 = Bt + (size_t)(rB + 64) * K + kslot * 8;
  const u16* b2 = Bt + (size_t)(rB + 128) * K + kslot * 8;
  const u16* b3 = Bt + (size_t)(rB + 192) * K + kslot * 8;

  const int arow = ((wr << 5) + l15) << 7;
  const int brow = ((wc << 6) + l15) << 7;
  const int swz0 = (quad ^ (l15 & 7)) << 4;
  const int swz1 = ((4 + quad) ^ (l15 & 7)) << 4;

  floatx4 acc[4][4];
#pragma unroll
  for (int i = 0; i < 4; i++)
#pragma unroll
    for (int j = 0; j < 4; j++) acc[i][j] = (floatx4){0.f, 0.f, 0.f, 0.f};

  const int nk = K >> 6;

  gl2lds16(a0, &As[0][tid * 8]);
  gl2lds16(a1, &As[0][4096 + tid * 8]);
  gl2lds16(b0, &Bs[0][0 * 4096 + tid * 8]);
  gl2lds16(b1, &Bs[0][1 * 4096 + tid * 8]);
  gl2lds16(b2, &Bs[0][2 * 4096 + tid * 8]);
  gl2lds16(b3, &Bs[0][3 * 4096 + tid * 8]);
  gl2lds16(b0 + 64, &Bs[1][0 * 4096 + tid * 8]);
  gl2lds16(b1 + 64, &Bs[1][1 * 4096 + tid * 8]);
  gl2lds16(b2 + 64, &Bs[1][2 * 4096 + tid * 8]);
  gl2lds16(b3 + 64, &Bs[1][3 * 4096 + tid * 8]);
  gl2lds16(a0 + 64, &As[1][tid * 8]);
  asm volatile("s_waitcnt vmcnt(5)" ::: "memory");
  __builtin_amdgcn_s_barrier();
  a0 += 128; a1 += 64;
  b0 += 128; b1 += 128; b2 += 128; b3 += 128;

#define LOAD_AR1(q)                                                            \
  ar[0] = *(const bf16x8*)(ab + ((q) >> 1) * 8192 + ((q) & 1) * 2048 + arow + swz0); \
  ar[1] = *(const bf16x8*)(ab + ((q) >> 1) * 8192 + ((q) & 1) * 2048 + arow + swz1);
#define MFMA_PH1(q)                                                            \
  __builtin_amdgcn_s_setprio(1);                                               \
  _Pragma("unroll") for (int nf = 0; nf < 4; nf++)                             \
    acc[q][nf] = __builtin_amdgcn_mfma_f32_16x16x32_bf16(                      \
        ar[0], br[nf][0], acc[q][nf], 0, 0, 0);                                \
  _Pragma("unroll") for (int nf = 0; nf < 4; nf++)                             \
    acc[q][nf] = __builtin_amdgcn_mfma_f32_16x16x32_bf16(                      \
        ar[1], br[nf][1], acc[q][nf], 0, 0, 0);                                \
  __builtin_amdgcn_s_setprio(0);

#pragma unroll 1
  for (int t = 0; t < nk; t++) {
    const char* ab = (const char*)As[t & 1];
    const char* bb = (const char*)Bs[t & 1];
    u16* An = As[(t + 1) & 1];
    u16* Ac = As[t & 1];
    u16* Bc = Bs[t & 1];
    const bool st1 = (t + 1 < nk), st2 = (t + 2 < nk);
    bf16x8 br[4][2], ar[2];

#pragma unroll
    for (int nf = 0; nf < 4; nf++) {
      br[nf][0] = *(const bf16x8*)(bb + nf * 2048 + brow + swz0);
      br[nf][1] = *(const bf16x8*)(bb + nf * 2048 + brow + swz1);
    }
    LOAD_AR1(0)
    if (st1) gl2lds16(a1, An + 4096 + tid * 8);
    __builtin_amdgcn_s_barrier();
    asm volatile("s_waitcnt lgkmcnt(0)" ::: "memory");
    MFMA_PH1(0)
    __builtin_amdgcn_s_barrier();

    LOAD_AR1(1)
    if (st2) {
      gl2lds16(b0, Bc + 0 * 4096 + tid * 8);
      gl2lds16(b1, Bc + 1 * 4096 + tid * 8);
    }
    __builtin_amdgcn_s_barrier();
    asm volatile("s_waitcnt lgkmcnt(0)" ::: "memory");
    MFMA_PH1(1)
    __builtin_amdgcn_s_barrier();

    LOAD_AR1(2)
    if (st2) {
      gl2lds16(b2, Bc + 2 * 4096 + tid * 8);
      gl2lds16(b3, Bc + 3 * 4096 + tid * 8);
    }
    __builtin_amdgcn_s_barrier();
    asm volatile("s_waitcnt lgkmcnt(0)" ::: "memory");
    MFMA_PH1(2)
    __builtin_amdgcn_s_barrier();

    LOAD_AR1(3)
    if (st2) gl2lds16(a0, Ac + tid * 8);
    __builtin_amdgcn_s_barrier();
    asm volatile("s_waitcnt lgkmcnt(0)" ::: "memory");
    MFMA_PH1(3)
    if (st2)
      asm volatile("s_waitcnt vmcnt(6)" ::: "memory");
    else
      asm volatile("s_waitcnt vmcnt(0)" ::: "memory");
    __builtin_amdgcn_s_barrier();

    a0 += 64; a1 += 64;
    b0 += 64; b1 += 64; b2 += 64; b3 += 64;
  }
#undef LOAD_AR1
#undef MFMA_PH1

  const int m0 = blockM + wr * 64 + quad * 4;
  const int n0 = blockN + wc * 64 + l15;
  if (MODE == 0) {
    u16* o0 = (u16*)o0v; u16* o1 = (u16*)o1v; u16* o2 = (u16*)o2v;
#pragma unroll
    for (int nf = 0; nf < 4; nf++) {
      int n = n0 + nf * 16;
      int sec = n >> 10, hh = (n >> 6) & 15, d = n & 63;
      u16* dst = (sec == 0) ? o0 : (sec == 1) ? o1 : o2;
#pragma unroll
      for (int mf = 0; mf < 4; mf++)
#pragma unroll
        for (int r = 0; r < 4; r++) {
          int m = m0 + mf * 16 + r;
          int b = m >> 11, tt = m & 2047;
          dst[((size_t)((b * 16 + hh) * 2048 + tt)) * 64 + d] = f2b(acc[mf][nf][r]);
        }
    }
  } else {
    float* o0 = (float*)o0v;
#pragma unroll
    for (int nf = 0; nf < 4; nf++) {
      int n = n0 + nf * 16;
      float bv = bias[n];
#pragma unroll
      for (int mf = 0; mf < 4; mf++)
#pragma unroll
        for (int r = 0; r < 4; r++) {
          int m = m0 + mf * 16 + r;
          float v = acc[mf][nf][r] + bv;
          o0[(size_t)m * N + n] = v > 0.f ? v : 0.f;
        }
    }
  }
}

// =============================================================================
// MFMA causal flash attention (round-2 verified inner loop, single-pass grid).
// Grid (64 bh, 16 j): block (x,y) handles q-rows [j*128, j*128+128), j=15-y.
// x-fastest dispatch => all j=15 (longest, 32 stages) blocks start first;
// bh's 16 blocks are 64 ids apart => same XCD slot (64%8==0) => K/V L2-local.
// 1024 blocks, 50KB LDS => 3 blocks/CU (12 waves/CU) vs round-2's grid-capped
// 2 blocks/CU. Inner loop unchanged from the verified round-2 kernel.
// =============================================================================
__global__ __launch_bounds__(256) void attn_mfma(
    const u16* __restrict__ Q, const u16* __restrict__ K,
    const u16* __restrict__ Vt, u16* __restrict__ out) {
  __shared__ __align__(16) u16 Kbuf[2][4096];
  __shared__ __align__(16) u16 Vbuf[2][4096];
  __shared__ __align__(16) u16 Plds[4][32][72];
  const int tid = threadIdx.x;
  const int wave = tid >> 6, lane = tid & 63;
  const int quad = lane >> 4, l15 = lane & 15;
  const int sx = l15 & 7;
  const int bh = blockIdx.x;
  const int j = 15 - blockIdx.y;      // longest-first
  const size_t qkb = (size_t)bh * CTX * 64;
  const size_t vb = (size_t)bh * 64 * CTX;

  const int ch0 = wave * 64 + lane;
  const int ch1 = 256 + ch0;
  const int r0 = ch0 >> 3, s0 = (ch0 & 7) ^ (r0 & 7);
  const int r1 = ch1 >> 3, s1 = (ch1 & 7) ^ (r1 & 7);
  const u16* kg0 = K + qkb + r0 * 64 + s0 * 8;
  const u16* kg1 = K + qkb + r1 * 64 + s1 * 8;
  const u16* vg0 = Vt + vb + (size_t)r0 * CTX + s0 * 8;
  const u16* vg1 = Vt + vb + (size_t)r1 * CTX + s1 * 8;

  const int qbase = j * 128 + wave * 32;
  const int NST = 2 * j + 2;
  const int nstw = 2 * j + (wave >> 1) + 1;

  bf16x8 qf[2][2];
#pragma unroll
  for (int mt = 0; mt < 2; mt++)
#pragma unroll
    for (int kc = 0; kc < 2; kc++)
      qf[mt][kc] = *(const bf16x8*)(Q + qkb + (size_t)(qbase + mt * 16 + l15) * 64 + kc * 32 + quad * 8);

  floatx4 o[2][4];
#pragma unroll
  for (int mt = 0; mt < 2; mt++)
#pragma unroll
    for (int dt = 0; dt < 4; dt++) o[mt][dt] = (floatx4){0.f, 0.f, 0.f, 0.f};
  float mrow[2] = {-1e30f, -1e30f};
  float lrow[2] = {0.f, 0.f};

  gl2lds16(kg0, &Kbuf[0][wave * 512]);
  gl2lds16(kg1, &Kbuf[0][2048 + wave * 512]);
  gl2lds16(vg0, &Vbuf[0][wave * 512]);
  gl2lds16(vg1, &Vbuf[0][2048 + wave * 512]);

#pragma unroll 1
  for (int st = 0; st < NST; st++) {
    __syncthreads();
    if (st + 1 < NST) {
      const int sb = (st + 1) * 64;
      const int b = (st + 1) & 1;
      gl2lds16(kg0 + sb * 64, &Kbuf[b][wave * 512]);
      gl2lds16(kg1 + sb * 64, &Kbuf[b][2048 + wave * 512]);
      gl2lds16(vg0 + sb, &Vbuf[b][wave * 512]);
      gl2lds16(vg1 + sb, &Vbuf[b][2048 + wave * 512]);
    }
    if (st >= nstw) continue;
    const int sbase = st * 64;
    const u16* kb = Kbuf[st & 1];
    const u16* vv = Vbuf[st & 1];

    floatx4 stf[2][4];
#pragma unroll
    for (int sc = 0; sc < 4; sc++) {
      const bf16x8* kr = (const bf16x8*)(kb + (sc * 16 + l15) * 64);
      bf16x8 k0 = kr[quad ^ sx];
      bf16x8 k1 = kr[(4 + quad) ^ sx];
#pragma unroll
      for (int mt = 0; mt < 2; mt++) {
        floatx4 z = (floatx4){0.f, 0.f, 0.f, 0.f};
        z = __builtin_amdgcn_mfma_f32_16x16x32_bf16(k0, qf[mt][0], z, 0, 0, 0);
        stf[mt][sc] = __builtin_amdgcn_mfma_f32_16x16x32_bf16(k1, qf[mt][1], z, 0, 0, 0);
      }
    }
    if (st == nstw - 1) {
#pragma unroll
      for (int mt = 0; mt < 2; mt++) {
        int qq = qbase + mt * 16 + l15;
#pragma unroll
        for (int sc = 0; sc < 4; sc++)
#pragma unroll
          for (int r = 0; r < 4; r++) {
            int s = sbase + sc * 16 + quad * 4 + r;
            if (s > qq) stf[mt][sc][r] = -1e30f;
          }
      }
    }
#pragma unroll
    for (int mt = 0; mt < 2; mt++) {
      floatx4 m4 = fmax4(fmax4(stf[mt][0], stf[mt][1]), fmax4(stf[mt][2], stf[mt][3]));
      float tm = fmaxf(fmaxf(m4[0], m4[1]), fmaxf(m4[2], m4[3]));
      tm = fmaxf(tm, __shfl_xor(tm, 16));
      tm = fmaxf(tm, __shfl_xor(tm, 32));
      // T13 defer-max: only rescale when the running max grew materially.
      if (!__all(tm <= mrow[mt] + 8.0f)) {
        float mnew = fmaxf(mrow[mt], tm);
        float alpha = exp2f((mrow[mt] - mnew) * C_SCALE);
        mrow[mt] = mnew;
        lrow[mt] *= alpha;
#pragma unroll
        for (int dt = 0; dt < 4; dt++) o[mt][dt] *= alpha;
      }
      const float mneg = -mrow[mt] * C_SCALE;
      float lsum = 0.f;
#pragma unroll
      for (int sc = 0; sc < 4; sc++) {
        floatx4 s4 = stf[mt][sc];
        float p0 = exp2f(fmaf(s4[0], C_SCALE, mneg));
        float p1 = exp2f(fmaf(s4[1], C_SCALE, mneg));
        float p2 = exp2f(fmaf(s4[2], C_SCALE, mneg));
        float p3 = exp2f(fmaf(s4[3], C_SCALE, mneg));
        lsum += (p0 + p1) + (p2 + p3);
        *(uint2*)&Plds[wave][mt * 16 + l15][sc * 16 + quad * 4] =
            make_uint2(cvtpk(p0, p1), cvtpk(p2, p3));
      }
      lrow[mt] += lsum;
    }
    asm volatile("s_waitcnt lgkmcnt(0)" ::: "memory");
#pragma unroll
    for (int sc2 = 0; sc2 < 2; sc2++) {
      bf16x8 pf[2];
#pragma unroll
      for (int mt = 0; mt < 2; mt++)
        pf[mt] = *(const bf16x8*)&Plds[wave][mt * 16 + l15][sc2 * 32 + quad * 8];
#pragma unroll
      for (int dt = 0; dt < 4; dt++) {
        const bf16x8* vr = (const bf16x8*)(vv + (dt * 16 + l15) * 64);
        bf16x8 vf = vr[(sc2 * 4 + quad) ^ sx];
#pragma unroll
        for (int mt = 0; mt < 2; mt++)
          o[mt][dt] = __builtin_amdgcn_mfma_f32_16x16x32_bf16(vf, pf[mt], o[mt][dt], 0, 0, 0);
      }
    }
  }

#pragma unroll
  for (int mt = 0; mt < 2; mt++) {
    float l = lrow[mt];
    l += __shfl_xor(l, 16);
    l += __shfl_xor(l, 32);
    float inv = 1.0f / l;
    int row = (bh >> 4) * CTX + qbase + mt * 16 + l15;
    u16* orow = out + (size_t)row * DMODEL + (bh & 15) * 64;
#pragma unroll
    for (int dt = 0; dt < 4; dt++) {
      floatx4 v = o[mt][dt];
      *(u32*)(orow + dt * 16 + quad * 4) = cvtpk(v[0] * inv, v[1] * inv);
      *(u32*)(orow + dt * 16 + quad * 4 + 2) = cvtpk(v[2] * inv, v[3] * inv);
    }
  }
}

extern "C" void kernel_launch(void* const* d_in, const int* in_sizes, int n_in,
                              void* d_out, int out_size, void* d_ws, size_t ws_size,
                              hipStream_t stream) {
  const float* x  = (const float*)d_in[0];
  const float* Wq = (const float*)d_in[1];
  const float* Wk = (const float*)d_in[2];
  const float* Wv = (const float*)d_in[3];
  const float* W1 = (const float*)d_in[4];
  const float* b1 = (const float*)d_in[5];
  const float* W2 = (const float*)d_in[6];
  const float* b2 = (const float*)d_in[7];
  float* out = (float*)d_out;

  u16* ws    = (u16*)d_ws;
  u16* W1t   = ws;                             // [4096][1024]
  u16* W2t   = W1t + (size_t)4096 * 1024;      // [1024][4096]
  u16* att   = W2t + (size_t)4096 * 1024;      // [B*T][1024]  (also v_tmp)
  u16* xb    = att + (size_t)MROWS * 1024;     // [B*T][1024]
  u16* Wqkvt = xb + (size_t)MROWS * 1024;      // [3072][1024]
  u16* q     = Wqkvt + (size_t)3072 * 1024;    // [B*H][T][64]
  u16* k     = q + (size_t)MROWS * 1024;       // [B*H][T][64]
  u16* vt    = k + (size_t)MROWS * 1024;       // [B*H][64][T]
  u16* v_tmp = att;                            // [B*H][T][64]
  u16* h     = xb;                             // [B*T][4096] overlaps xb..vt

  cvt_f32_bf16<<<MROWS * 1024 / 1024, 256, 0, stream>>>(x, xb);

  dim3 tb(32, 8);
  transpose_qkv<<<dim3(2, 32, 48), tb, 0, stream>>>(Wq, Wk, Wv, Wqkvt);
  transpose_f32_bf16<<<dim3(128, 32, 1), tb, 0, stream>>>(W1, W1t, 1024, 4096, 0, 0);
  transpose_f32_bf16<<<dim3(32, 128, 1), tb, 0, stream>>>(W2, W2t, 4096, 1024, 0, 0);

  // QKV projection: [8192][1024] x [3072][1024]^T -> q/k/v (coalesced scatter)
  // 128x256 tiles: 64 x 12 = 768 wg = 3 exact chip rounds (was 1.5 at 256^2)
  gemm128<0><<<768, 512, 0, stream>>>(xb, Wqkvt, nullptr, q, k, v_tmp, 3072, 1024);
  // v [BH][T][64] -> vt [BH][64][T]
  transpose_v_bf16<<<dim3(2, 64, 64), tb, 0, stream>>>(v_tmp, vt);
  // MFMA causal flash attention -> att [B*T][1024]
  attn_mfma<<<dim3(64, 16), 256, 0, stream>>>(q, k, vt, att);
  // FFN1: att @ W1 + b1 -> h (bf16)
  gemm256<1><<<512, 512, 0, stream>>>(att, W1t, b1, h, nullptr, nullptr, 4096, 1024);
  // FFN2: relu(h @ W2 + b2) -> out (fp32), 128x256 tiles = 256 wg (full chip)
  gemm128<2><<<256, 512, 0, stream>>>(h, W2t, b2, out, nullptr, nullptr, 1024, 4096);
}

// Round 5
// 463.237 us; speedup vs baseline: 1.2190x; 1.0073x over previous
//
#include <hip/hip_runtime.h>
#include <hip/hip_bf16.h>

typedef unsigned short u16;
typedef unsigned int u32;
typedef short bf16x8 __attribute__((ext_vector_type(8)));
typedef float floatx4 __attribute__((ext_vector_type(4)));

#define CTX 2048
#define HEADSZ 64
#define NHEAD 16
#define DMODEL 1024
#define DFF 4096
#define MROWS 8192  // B*T
#define C_SCALE 0.18033688011112042f  // 0.125 * log2(e)

__device__ __forceinline__ u16 f2b(float f) {
  union { float f; u32 i; } x; x.f = f;
  u32 i = x.i;
  return (u16)((i + 0x7fffu + ((i >> 16) & 1u)) >> 16);  // RNE
}
__device__ __forceinline__ u32 pack2(float a, float b) {
  return (u32)f2b(a) | ((u32)f2b(b) << 16);
}
__device__ __forceinline__ u32 cvtpk(float a, float b) {
  u32 r;
  asm("v_cvt_pk_bf16_f32 %0, %1, %2" : "=v"(r) : "v"(a), "v"(b));
  return r;
}
__device__ __forceinline__ floatx4 fmax4(floatx4 a, floatx4 b) {
  floatx4 r;
  r[0] = fmaxf(a[0], b[0]); r[1] = fmaxf(a[1], b[1]);
  r[2] = fmaxf(a[2], b[2]); r[3] = fmaxf(a[3], b[3]);
  return r;
}

__device__ __forceinline__ void gl2lds16(const u16* g, u16* l) {
  __builtin_amdgcn_global_load_lds(
      (const __attribute__((address_space(1))) void*)g,
      (__attribute__((address_space(3))) void*)l, 16, 0, 0);
}

// ---------------- elementwise fp32 -> bf16 (4 elems/thread) -------------------
__global__ __launch_bounds__(256) void cvt_f32_bf16(const float* __restrict__ in,
                                                    u16* __restrict__ out) {
  int i = (blockIdx.x * 256 + threadIdx.x) * 4;
  float4 v = *(const float4*)(in + i);
  *(uint2*)(out + i) = make_uint2(pack2(v.x, v.y), pack2(v.z, v.w));
}

// ------------- batched transpose: out_bf16[z][c][r] = in_f32[z][r][c] ---------
__global__ void transpose_f32_bf16(const float* __restrict__ in, u16* __restrict__ out,
                                   int R, int C, long ibs, long obs) {
  __shared__ u16 tile[32][33];
  const float* ip = in + (size_t)blockIdx.z * ibs;
  u16* op = out + (size_t)blockIdx.z * obs;
  int c0 = blockIdx.x * 32, r0 = blockIdx.y * 32;
  int tx = threadIdx.x, ty = threadIdx.y;
#pragma unroll
  for (int i = 0; i < 32; i += 8)
    tile[ty + i][tx] = f2b(ip[(size_t)(r0 + ty + i) * C + (c0 + tx)]);
  __syncthreads();
#pragma unroll
  for (int i = 0; i < 32; i += 8)
    op[(size_t)(c0 + ty + i) * R + (r0 + tx)] = tile[tx][ty + i];
}

// ------ combined per-head transpose of Wq/Wk/Wv [16][1024][64] fp32
//        -> Wqkvt rows sec*1024 + head*64 .. ( [64][1024] per head, bf16 )
__global__ void transpose_qkv(const float* __restrict__ Wq, const float* __restrict__ Wk,
                              const float* __restrict__ Wv, u16* __restrict__ out) {
  __shared__ u16 tile[32][33];
  int z = blockIdx.z;               // 0..47
  int sec = z >> 4, hh = z & 15;
  const float* ip = (sec == 0 ? Wq : sec == 1 ? Wk : Wv) + (size_t)hh * 65536;
  u16* op = out + (size_t)(sec * 16 + hh) * 65536;
  int c0 = blockIdx.x * 32, r0 = blockIdx.y * 32;
  int tx = threadIdx.x, ty = threadIdx.y;
#pragma unroll
  for (int i = 0; i < 32; i += 8)
    tile[ty + i][tx] = f2b(ip[(size_t)(r0 + ty + i) * 64 + (c0 + tx)]);
  __syncthreads();
#pragma unroll
  for (int i = 0; i < 32; i += 8)
    op[(size_t)(c0 + ty + i) * 1024 + (r0 + tx)] = tile[tx][ty + i];
}

// ------------- bf16 transpose: v [BH][2048][64] -> vt [BH][64][2048] ----------
__global__ void transpose_v_bf16(const u16* __restrict__ in, u16* __restrict__ out) {
  __shared__ u16 tile[32][33];
  const u16* ip = in + (size_t)blockIdx.z * (CTX * 64);
  u16* op = out + (size_t)blockIdx.z * (CTX * 64);
  int c0 = blockIdx.x * 32, r0 = blockIdx.y * 32;
  int tx = threadIdx.x, ty = threadIdx.y;
#pragma unroll
  for (int i = 0; i < 32; i += 8)
    tile[ty + i][tx] = ip[(size_t)(r0 + ty + i) * 64 + (c0 + tx)];
  __syncthreads();
#pragma unroll
  for (int i = 0; i < 32; i += 8)
    op[(size_t)(c0 + ty + i) * CTX + (r0 + tx)] = tile[tx][ty + i];
}

// =============================================================================
// 256x256 8-phase GEMM. Round-4 changes:
//  - staging earliness: ph1 stages all B(t+2), ph2 stages A01(t+2), ph3 none
//    (race-free: regions' readers are >=1 barrier earlier; FIFO: vmcnt(6)
//    at end of t still drains exactly all of tile t+1's 8 loads).
//  - MODE 1 epilogue: LDS-coalesced (wave-private swizzled stage + b128
//    row readback + 128B-contiguous dwordx4 stores). Fixes the 2.5x HBM
//    write amplification measured via WRITE_SIZE (163 MB for 64 MB output).
// =============================================================================
template <int MODE>
__global__ __launch_bounds__(512, 2) void gemm256(
    const u16* __restrict__ A, const u16* __restrict__ Bt,
    const float* __restrict__ bias,
    void* __restrict__ o0v, void* __restrict__ o1v, void* __restrict__ o2v,
    int N, int K) {
  __shared__ __align__(16) u16 As[2][16384];
  __shared__ __align__(16) u16 Bs[2][16384];
  const int tid = threadIdx.x;
  const int quad = (tid >> 4) & 3, l15 = tid & 15;
  const int wave = tid >> 6;
  const int wr = wave >> 2, wc = wave & 3;

  const int id = blockIdx.x;
  const int blockM = (((id & 7) << 2) | ((id >> 3) & 3)) << 8;
  const int blockN = (id >> 5) << 8;

  const int sub = tid >> 3;                    // 0..63
  const int kslot = (tid & 7) ^ (sub & 7);     // pre-swizzled global k-slot
  const int rA = blockM + ((sub >> 5) << 7) + (sub & 31);
  const u16* a0 = A + (size_t)(rA + 0) * K + kslot * 8;
  const u16* a1 = A + (size_t)(rA + 32) * K + kslot * 8;
  const u16* a2 = A + (size_t)(rA + 64) * K + kslot * 8;
  const u16* a3 = A + (size_t)(rA + 96) * K + kslot * 8;
  const int rB = blockN + sub;
  const u16* b0 = Bt + (size_t)(rB + 0) * K + kslot * 8;
  const u16* b1 = Bt + (size_t)(rB + 64) * K + kslot * 8;
  const u16* b2 = Bt + (size_t)(rB + 128) * K + kslot * 8;
  const u16* b3 = Bt + (size_t)(rB + 192) * K + kslot * 8;

  const int arow = ((wr << 5) + l15) << 7;
  const int brow = ((wc << 6) + l15) << 7;
  const int swz0 = (quad ^ (l15 & 7)) << 4;
  const int swz1 = ((4 + quad) ^ (l15 & 7)) << 4;

  floatx4 acc[8][4];
#pragma unroll
  for (int i = 0; i < 8; i++)
#pragma unroll
    for (int j = 0; j < 4; j++) acc[i][j] = (floatx4){0.f, 0.f, 0.f, 0.f};

  const int nk = K >> 6;

  gl2lds16(a0, &As[0][0 * 4096 + tid * 8]);
  gl2lds16(a1, &As[0][1 * 4096 + tid * 8]);
  gl2lds16(a2, &As[0][2 * 4096 + tid * 8]);
  gl2lds16(a3, &As[0][3 * 4096 + tid * 8]);
  gl2lds16(b0, &Bs[0][0 * 4096 + tid * 8]);
  gl2lds16(b1, &Bs[0][1 * 4096 + tid * 8]);
  gl2lds16(b2, &Bs[0][2 * 4096 + tid * 8]);
  gl2lds16(b3, &Bs[0][3 * 4096 + tid * 8]);
  gl2lds16(b0 + 64, &Bs[1][0 * 4096 + tid * 8]);
  gl2lds16(b1 + 64, &Bs[1][1 * 4096 + tid * 8]);
  gl2lds16(b2 + 64, &Bs[1][2 * 4096 + tid * 8]);
  gl2lds16(b3 + 64, &Bs[1][3 * 4096 + tid * 8]);
  gl2lds16(a0 + 64, &As[1][0 * 4096 + tid * 8]);
  gl2lds16(a1 + 64, &As[1][1 * 4096 + tid * 8]);
  asm volatile("s_waitcnt vmcnt(6)" ::: "memory");
  __builtin_amdgcn_s_barrier();
  a0 += 128; a1 += 128; a2 += 64; a3 += 64;
  b0 += 128; b1 += 128; b2 += 128; b3 += 128;

#define LOAD_AR(q)                                                             \
  _Pragma("unroll") for (int mm = 0; mm < 2; mm++) {                           \
    ar[mm][0] = *(const bf16x8*)(ab + (q) * 8192 + mm * 2048 + arow + swz0);   \
    ar[mm][1] = *(const bf16x8*)(ab + (q) * 8192 + mm * 2048 + arow + swz1);   \
  }
#define MFMA_PH(q)                                                             \
  __builtin_amdgcn_s_setprio(1);                                               \
  _Pragma("unroll") for (int mm = 0; mm < 2; mm++)                             \
  _Pragma("unroll") for (int nf = 0; nf < 4; nf++)                             \
    acc[(q) * 2 + mm][nf] = __builtin_amdgcn_mfma_f32_16x16x32_bf16(           \
        ar[mm][0], br[nf][0], acc[(q) * 2 + mm][nf], 0, 0, 0);                 \
  _Pragma("unroll") for (int mm = 0; mm < 2; mm++)                             \
  _Pragma("unroll") for (int nf = 0; nf < 4; nf++)                             \
    acc[(q) * 2 + mm][nf] = __builtin_amdgcn_mfma_f32_16x16x32_bf16(           \
        ar[mm][1], br[nf][1], acc[(q) * 2 + mm][nf], 0, 0, 0);                 \
  __builtin_amdgcn_s_setprio(0);

#pragma unroll 1
  for (int t = 0; t < nk; t++) {
    const char* ab = (const char*)As[t & 1];
    const char* bb = (const char*)Bs[t & 1];
    u16* An = As[(t + 1) & 1];
    u16* Ac = As[t & 1];
    u16* Bc = Bs[t & 1];
    const bool st1 = (t + 1 < nk), st2 = (t + 2 < nk);
    bf16x8 br[4][2], ar[2][2];

    // ph0: all B-frags + A(mf01); stage A23(t+1) -> other buf
#pragma unroll
    for (int nf = 0; nf < 4; nf++) {
      br[nf][0] = *(const bf16x8*)(bb + nf * 2048 + brow + swz0);
      br[nf][1] = *(const bf16x8*)(bb + nf * 2048 + brow + swz1);
    }
    LOAD_AR(0)
    if (st1) {
      gl2lds16(a2, An + 2 * 4096 + tid * 8);
      gl2lds16(a3, An + 3 * 4096 + tid * 8);
    }
    __builtin_amdgcn_s_barrier();
    asm volatile("s_waitcnt lgkmcnt(0)" ::: "memory");
    MFMA_PH(0)
    __builtin_amdgcn_s_barrier();

    // ph1: A(mf23); stage ALL B(t+2) -> cur buf (B read only at ph0)
    LOAD_AR(1)
    if (st2) {
      gl2lds16(b0, Bc + 0 * 4096 + tid * 8);
      gl2lds16(b1, Bc + 1 * 4096 + tid * 8);
      gl2lds16(b2, Bc + 2 * 4096 + tid * 8);
      gl2lds16(b3, Bc + 3 * 4096 + tid * 8);
    }
    __builtin_amdgcn_s_barrier();
    asm volatile("s_waitcnt lgkmcnt(0)" ::: "memory");
    MFMA_PH(1)
    __builtin_amdgcn_s_barrier();

    // ph2: A(mf45); stage A01(t+2) -> cur buf (regions 0,1 read at ph0/ph1)
    LOAD_AR(2)
    if (st2) {
      gl2lds16(a0, Ac + 0 * 4096 + tid * 8);
      gl2lds16(a1, Ac + 1 * 4096 + tid * 8);
    }
    __builtin_amdgcn_s_barrier();
    asm volatile("s_waitcnt lgkmcnt(0)" ::: "memory");
    MFMA_PH(2)
    __builtin_amdgcn_s_barrier();

    // ph3: A(mf67); counted drain (FIFO: drains exactly tile t+1's 8 loads)
    LOAD_AR(3)
    __builtin_amdgcn_s_barrier();
    asm volatile("s_waitcnt lgkmcnt(0)" ::: "memory");
    MFMA_PH(3)
    if (st2)
      asm volatile("s_waitcnt vmcnt(6)" ::: "memory");
    else
      asm volatile("s_waitcnt vmcnt(0)" ::: "memory");
    __builtin_amdgcn_s_barrier();

    a0 += 64; a1 += 64; a2 += 64; a3 += 64;
    b0 += 64; b1 += 64; b2 += 64; b3 += 64;
  }
#undef LOAD_AR
#undef MFMA_PH

  const int m0 = blockM + wr * 128 + quad * 4;
  const int n0 = blockN + wc * 64 + l15;
  if (MODE == 1) {
    // LDS-coalesced bf16 epilogue: wave-private 16KB region (waves 0-3 in As,
    // 4-7 in Bs), XOR slot-swizzle, b128 readback, 128B-contiguous stores.
    u16* o0 = (u16*)o0v;
    const int lane = tid & 63;
    u16* buf = (wave < 4) ? ((u16*)As[0] + wave * 8192)
                          : ((u16*)Bs[0] + (wave - 4) * 8192);
#pragma unroll
    for (int nf = 0; nf < 4; nf++) {
      float bv = bias[n0 + nf * 16];
#pragma unroll
      for (int mf = 0; mf < 8; mf++)
#pragma unroll
        for (int r = 0; r < 4; r++) {
          int row = mf * 16 + quad * 4 + r;
          int col2 = (nf * 16 + l15) ^ ((row & 7) << 3);  // u16 units
          buf[row * 64 + col2] = f2b(acc[mf][nf][r] + bv);
        }
    }
    const int lr = lane >> 3, lc = lane & 7;
    const int mb = blockM + wr * 128;
    const size_t nb = blockN + wc * 64;
#pragma unroll
    for (int i = 0; i < 16; i++) {
      int row = i * 8 + lr;
      uint4 v = *(const uint4*)(buf + row * 64 + ((lc ^ lr) << 3));
      *(uint4*)(o0 + (size_t)(mb + row) * N + nb + lc * 8) = v;
    }
  } else {
    float* o0 = (float*)o0v;
#pragma unroll
    for (int nf = 0; nf < 4; nf++) {
      int n = n0 + nf * 16;
      float bv = bias[n];
#pragma unroll
      for (int mf = 0; mf < 8; mf++)
#pragma unroll
        for (int r = 0; r < 4; r++) {
          int m = m0 + mf * 16 + r;
          float v = acc[mf][nf][r] + bv;
          o0[(size_t)m * N + n] = v > 0.f ? v : 0.f;
        }
    }
  }
}

// =============================================================================
// 128x256 8-phase GEMM. Round-4 changes: staging earliness (ph1 all B(t+2),
// ph2 A0(t+2); vmcnt(5) drains exactly tile t+1's 6 loads) and MODE-0
// LDS-coalesced epilogue (1KB-contiguous q/k/v chunks per store quad).
//   MODE 0: scatter bf16 -> q/k/v [B,H,T,64]   (QKV: 768 wg = 3 rounds)
//   MODE 2: f32 relu(acc+bias)                 (FFN2: 256 wg = 1 round)
// =============================================================================
template <int MODE>
__global__ __launch_bounds__(512, 2) void gemm128(
    const u16* __restrict__ A, const u16* __restrict__ Bt,
    const float* __restrict__ bias,
    void* __restrict__ o0v, void* __restrict__ o1v, void* __restrict__ o2v,
    int N, int K) {
  __shared__ __align__(16) u16 As[2][8192];
  __shared__ __align__(16) u16 Bs[2][16384];
  const int tid = threadIdx.x;
  const int quad = (tid >> 4) & 3, l15 = tid & 15;
  const int wave = tid >> 6;
  const int wr = wave >> 2, wc = wave & 3;

  const int id = blockIdx.x;
  const int blockM = (((id & 7) << 3) | ((id >> 3) & 7)) << 7;  // 64 M-tiles
  const int blockN = (id >> 6) << 8;

  const int sub = tid >> 3;
  const int kslot = (tid & 7) ^ (sub & 7);
  const int rA = blockM + ((sub >> 5) << 6) + (sub & 31);
  const u16* a0 = A + (size_t)(rA + 0) * K + kslot * 8;
  const u16* a1 = A + (size_t)(rA + 32) * K + kslot * 8;
  const int rB = blockN + sub;
  const u16* b0 = Bt + (size_t)(rB + 0) * K + kslot * 8;
  const u16* b1 = Bt + (size_t)(rB + 64) * K + kslot * 8;
  const u16* b2 = Bt + (size_t)(rB + 128) * K + kslot * 8;
  const u16* b3 = Bt + (size_t)(rB + 192) * K + kslot * 8;

  const int arow = ((wr << 5) + l15) << 7;
  const int brow = ((wc << 6) + l15) << 7;
  const int swz0 = (quad ^ (l15 & 7)) << 4;
  const int swz1 = ((4 + quad) ^ (l15 & 7)) << 4;

  floatx4 acc[4][4];
#pragma unroll
  for (int i = 0; i < 4; i++)
#pragma unroll
    for (int j = 0; j < 4; j++) acc[i][j] = (floatx4){0.f, 0.f, 0.f, 0.f};

  const int nk = K >> 6;

  gl2lds16(a0, &As[0][tid * 8]);
  gl2lds16(a1, &As[0][4096 + tid * 8]);
  gl2lds16(b0, &Bs[0][0 * 4096 + tid * 8]);
  gl2lds16(b1, &Bs[0][1 * 4096 + tid * 8]);
  gl2lds16(b2, &Bs[0][2 * 4096 + tid * 8]);
  gl2lds16(b3, &Bs[0][3 * 4096 + tid * 8]);
  gl2lds16(b0 + 64, &Bs[1][0 * 4096 + tid * 8]);
  gl2lds16(b1 + 64, &Bs[1][1 * 4096 + tid * 8]);
  gl2lds16(b2 + 64, &Bs[1][2 * 4096 + tid * 8]);
  gl2lds16(b3 + 64, &Bs[1][3 * 4096 + tid * 8]);
  gl2lds16(a0 + 64, &As[1][tid * 8]);
  asm volatile("s_waitcnt vmcnt(5)" ::: "memory");
  __builtin_amdgcn_s_barrier();
  a0 += 128; a1 += 64;
  b0 += 128; b1 += 128; b2 += 128; b3 += 128;

#define LOAD_AR1(q)                                                            \
  ar[0] = *(const bf16x8*)(ab + ((q) >> 1) * 8192 + ((q) & 1) * 2048 + arow + swz0); \
  ar[1] = *(const bf16x8*)(ab + ((q) >> 1) * 8192 + ((q) & 1) * 2048 + arow + swz1);
#define MFMA_PH1(q)                                                            \
  __builtin_amdgcn_s_setprio(1);                                               \
  _Pragma("unroll") for (int nf = 0; nf < 4; nf++)                             \
    acc[q][nf] = __builtin_amdgcn_mfma_f32_16x16x32_bf16(                      \
        ar[0], br[nf][0], acc[q][nf], 0, 0, 0);                                \
  _Pragma("unroll") for (int nf = 0; nf < 4; nf++)                             \
    acc[q][nf] = __builtin_amdgcn_mfma_f32_16x16x32_bf16(                      \
        ar[1], br[nf][1], acc[q][nf], 0, 0, 0);                                \
  __builtin_amdgcn_s_setprio(0);

#pragma unroll 1
  for (int t = 0; t < nk; t++) {
    const char* ab = (const char*)As[t & 1];
    const char* bb = (const char*)Bs[t & 1];
    u16* An = As[(t + 1) & 1];
    u16* Ac = As[t & 1];
    u16* Bc = Bs[t & 1];
    const bool st1 = (t + 1 < nk), st2 = (t + 2 < nk);
    bf16x8 br[4][2], ar[2];

    // ph0: all B-frags + A(mf0); stage A1(t+1) -> other buf
#pragma unroll
    for (int nf = 0; nf < 4; nf++) {
      br[nf][0] = *(const bf16x8*)(bb + nf * 2048 + brow + swz0);
      br[nf][1] = *(const bf16x8*)(bb + nf * 2048 + brow + swz1);
    }
    LOAD_AR1(0)
    if (st1) gl2lds16(a1, An + 4096 + tid * 8);
    __builtin_amdgcn_s_barrier();
    asm volatile("s_waitcnt lgkmcnt(0)" ::: "memory");
    MFMA_PH1(0)
    __builtin_amdgcn_s_barrier();

    // ph1: A(mf1); stage ALL B(t+2) -> cur buf (B read only at ph0)
    LOAD_AR1(1)
    if (st2) {
      gl2lds16(b0, Bc + 0 * 4096 + tid * 8);
      gl2lds16(b1, Bc + 1 * 4096 + tid * 8);
      gl2lds16(b2, Bc + 2 * 4096 + tid * 8);
      gl2lds16(b3, Bc + 3 * 4096 + tid * 8);
    }
    __builtin_amdgcn_s_barrier();
    asm volatile("s_waitcnt lgkmcnt(0)" ::: "memory");
    MFMA_PH1(1)
    __builtin_amdgcn_s_barrier();

    // ph2: A(mf2); stage A0(t+2) -> cur buf (region 0 read at ph0/ph1)
    LOAD_AR1(2)
    if (st2) gl2lds16(a0, Ac + tid * 8);
    __builtin_amdgcn_s_barrier();
    asm volatile("s_waitcnt lgkmcnt(0)" ::: "memory");
    MFMA_PH1(2)
    __builtin_amdgcn_s_barrier();

    // ph3: A(mf3); counted drain (FIFO: drains exactly tile t+1's 6 loads)
    LOAD_AR1(3)
    __builtin_amdgcn_s_barrier();
    asm volatile("s_waitcnt lgkmcnt(0)" ::: "memory");
    MFMA_PH1(3)
    if (st2)
      asm volatile("s_waitcnt vmcnt(5)" ::: "memory");
    else
      asm volatile("s_waitcnt vmcnt(0)" ::: "memory");
    __builtin_amdgcn_s_barrier();

    a0 += 64; a1 += 64;
    b0 += 64; b1 += 64; b2 += 64; b3 += 64;
  }
#undef LOAD_AR1
#undef MFMA_PH1

  const int m0 = blockM + wr * 64 + quad * 4;
  const int n0 = blockN + wc * 64 + l15;
  if (MODE == 0) {
    // LDS-coalesced scatter: wave-private 8KB region in Bs; each wave's
    // subtile maps to ONE head's contiguous [64 rows][128B] block in q/k/v.
    u16* o0 = (u16*)o0v; u16* o1 = (u16*)o1v; u16* o2 = (u16*)o2v;
    const int lane = tid & 63;
    u16* buf = (u16*)Bs[0] + wave * 4096;
#pragma unroll
    for (int nf = 0; nf < 4; nf++)
#pragma unroll
      for (int mf = 0; mf < 4; mf++)
#pragma unroll
        for (int r = 0; r < 4; r++) {
          int row = mf * 16 + quad * 4 + r;
          int col2 = (nf * 16 + l15) ^ ((row & 7) << 3);
          buf[row * 64 + col2] = f2b(acc[mf][nf][r]);
        }
    const int n0w = blockN + wc * 64;
    const int sec = n0w >> 10, hh = (n0w >> 6) & 15;
    u16* dst = (sec == 0) ? o0 : (sec == 1) ? o1 : o2;
    const int lr = lane >> 3, lc = lane & 7;
    const int m0w = blockM + wr * 64;
    const int b = m0w >> 11, t0 = m0w & 2047;
    u16* base = dst + ((size_t)((b * 16 + hh) * 2048 + t0)) * 64 + lc * 8;
#pragma unroll
    for (int i = 0; i < 8; i++) {
      int row = i * 8 + lr;
      uint4 v = *(const uint4*)(buf + row * 64 + ((lc ^ lr) << 3));
      *(uint4*)(base + (size_t)row * 64) = v;
    }
  } else {
    float* o0 = (float*)o0v;
#pragma unroll
    for (int nf = 0; nf < 4; nf++) {
      int n = n0 + nf * 16;
      float bv = bias[n];
#pragma unroll
      for (int mf = 0; mf < 4; mf++)
#pragma unroll
        for (int r = 0; r < 4; r++) {
          int m = m0 + mf * 16 + r;
          float v = acc[mf][nf][r] + bv;
          o0[(size_t)m * N + n] = v > 0.f ? v : 0.f;
        }
    }
  }
}

// =============================================================================
// MFMA causal flash attention (round-2 verified inner loop, single-pass grid).
// Grid (64 bh, 16 j): block (x,y) handles q-rows [j*128, +128), j=15-y.
// x-fastest dispatch => all j=15 (longest) blocks start first; bh's 16 blocks
// are 64 ids apart => same XCD slot => K/V L2-local. 3 blocks/CU.
// =============================================================================
__global__ __launch_bounds__(256) void attn_mfma(
    const u16* __restrict__ Q, const u16* __restrict__ K,
    const u16* __restrict__ Vt, u16* __restrict__ out) {
  __shared__ __align__(16) u16 Kbuf[2][4096];
  __shared__ __align__(16) u16 Vbuf[2][4096];
  __shared__ __align__(16) u16 Plds[4][32][72];
  const int tid = threadIdx.x;
  const int wave = tid >> 6, lane = tid & 63;
  const int quad = lane >> 4, l15 = lane & 15;
  const int sx = l15 & 7;
  const int bh = blockIdx.x;
  const int j = 15 - blockIdx.y;      // longest-first
  const size_t qkb = (size_t)bh * CTX * 64;
  const size_t vb = (size_t)bh * 64 * CTX;

  const int ch0 = wave * 64 + lane;
  const int ch1 = 256 + ch0;
  const int r0 = ch0 >> 3, s0 = (ch0 & 7) ^ (r0 & 7);
  const int r1 = ch1 >> 3, s1 = (ch1 & 7) ^ (r1 & 7);
  const u16* kg0 = K + qkb + r0 * 64 + s0 * 8;
  const u16* kg1 = K + qkb + r1 * 64 + s1 * 8;
  const u16* vg0 = Vt + vb + (size_t)r0 * CTX + s0 * 8;
  const u16* vg1 = Vt + vb + (size_t)r1 * CTX + s1 * 8;

  const int qbase = j * 128 + wave * 32;
  const int NST = 2 * j + 2;
  const int nstw = 2 * j + (wave >> 1) + 1;

  bf16x8 qf[2][2];
#pragma unroll
  for (int mt = 0; mt < 2; mt++)
#pragma unroll
    for (int kc = 0; kc < 2; kc++)
      qf[mt][kc] = *(const bf16x8*)(Q + qkb + (size_t)(qbase + mt * 16 + l15) * 64 + kc * 32 + quad * 8);

  floatx4 o[2][4];
#pragma unroll
  for (int mt = 0; mt < 2; mt++)
#pragma unroll
    for (int dt = 0; dt < 4; dt++) o[mt][dt] = (floatx4){0.f, 0.f, 0.f, 0.f};
  float mrow[2] = {-1e30f, -1e30f};
  float lrow[2] = {0.f, 0.f};

  gl2lds16(kg0, &Kbuf[0][wave * 512]);
  gl2lds16(kg1, &Kbuf[0][2048 + wave * 512]);
  gl2lds16(vg0, &Vbuf[0][wave * 512]);
  gl2lds16(vg1, &Vbuf[0][2048 + wave * 512]);

#pragma unroll 1
  for (int st = 0; st < NST; st++) {
    __syncthreads();
    if (st + 1 < NST) {
      const int sb = (st + 1) * 64;
      const int b = (st + 1) & 1;
      gl2lds16(kg0 + sb * 64, &Kbuf[b][wave * 512]);
      gl2lds16(kg1 + sb * 64, &Kbuf[b][2048 + wave * 512]);
      gl2lds16(vg0 + sb, &Vbuf[b][wave * 512]);
      gl2lds16(vg1 + sb, &Vbuf[b][2048 + wave * 512]);
    }
    if (st >= nstw) continue;
    const int sbase = st * 64;
    const u16* kb = Kbuf[st & 1];
    const u16* vv = Vbuf[st & 1];

    floatx4 stf[2][4];
#pragma unroll
    for (int sc = 0; sc < 4; sc++) {
      const bf16x8* kr = (const bf16x8*)(kb + (sc * 16 + l15) * 64);
      bf16x8 k0 = kr[quad ^ sx];
      bf16x8 k1 = kr[(4 + quad) ^ sx];
#pragma unroll
      for (int mt = 0; mt < 2; mt++) {
        floatx4 z = (floatx4){0.f, 0.f, 0.f, 0.f};
        z = __builtin_amdgcn_mfma_f32_16x16x32_bf16(k0, qf[mt][0], z, 0, 0, 0);
        stf[mt][sc] = __builtin_amdgcn_mfma_f32_16x16x32_bf16(k1, qf[mt][1], z, 0, 0, 0);
      }
    }
    if (st == nstw - 1) {
#pragma unroll
      for (int mt = 0; mt < 2; mt++) {
        int qq = qbase + mt * 16 + l15;
#pragma unroll
        for (int sc = 0; sc < 4; sc++)
#pragma unroll
          for (int r = 0; r < 4; r++) {
            int s = sbase + sc * 16 + quad * 4 + r;
            if (s > qq) stf[mt][sc][r] = -1e30f;
          }
      }
    }
#pragma unroll
    for (int mt = 0; mt < 2; mt++) {
      floatx4 m4 = fmax4(fmax4(stf[mt][0], stf[mt][1]), fmax4(stf[mt][2], stf[mt][3]));
      float tm = fmaxf(fmaxf(m4[0], m4[1]), fmaxf(m4[2], m4[3]));
      tm = fmaxf(tm, __shfl_xor(tm, 16));
      tm = fmaxf(tm, __shfl_xor(tm, 32));
      // T13 defer-max: only rescale when the running max grew materially.
      if (!__all(tm <= mrow[mt] + 8.0f)) {
        float mnew = fmaxf(mrow[mt], tm);
        float alpha = exp2f((mrow[mt] - mnew) * C_SCALE);
        mrow[mt] = mnew;
        lrow[mt] *= alpha;
#pragma unroll
        for (int dt = 0; dt < 4; dt++) o[mt][dt] *= alpha;
      }
      const float mneg = -mrow[mt] * C_SCALE;
      float lsum = 0.f;
#pragma unroll
      for (int sc = 0; sc < 4; sc++) {
        floatx4 s4 = stf[mt][sc];
        float p0 = exp2f(fmaf(s4[0], C_SCALE, mneg));
        float p1 = exp2f(fmaf(s4[1], C_SCALE, mneg));
        float p2 = exp2f(fmaf(s4[2], C_SCALE, mneg));
        float p3 = exp2f(fmaf(s4[3], C_SCALE, mneg));
        lsum += (p0 + p1) + (p2 + p3);
        *(uint2*)&Plds[wave][mt * 16 + l15][sc * 16 + quad * 4] =
            make_uint2(cvtpk(p0, p1), cvtpk(p2, p3));
      }
      lrow[mt] += lsum;
    }
    asm volatile("s_waitcnt lgkmcnt(0)" ::: "memory");
#pragma unroll
    for (int sc2 = 0; sc2 < 2; sc2++) {
      bf16x8 pf[2];
#pragma unroll
      for (int mt = 0; mt < 2; mt++)
        pf[mt] = *(const bf16x8*)&Plds[wave][mt * 16 + l15][sc2 * 32 + quad * 8];
#pragma unroll
      for (int dt = 0; dt < 4; dt++) {
        const bf16x8* vr = (const bf16x8*)(vv + (dt * 16 + l15) * 64);
        bf16x8 vf = vr[(sc2 * 4 + quad) ^ sx];
#pragma unroll
        for (int mt = 0; mt < 2; mt++)
          o[mt][dt] = __builtin_amdgcn_mfma_f32_16x16x32_bf16(vf, pf[mt], o[mt][dt], 0, 0, 0);
      }
    }
  }

#pragma unroll
  for (int mt = 0; mt < 2; mt++) {
    float l = lrow[mt];
    l += __shfl_xor(l, 16);
    l += __shfl_xor(l, 32);
    float inv = 1.0f / l;
    int row = (bh >> 4) * CTX + qbase + mt * 16 + l15;
    u16* orow = out + (size_t)row * DMODEL + (bh & 15) * 64;
#pragma unroll
    for (int dt = 0; dt < 4; dt++) {
      floatx4 v = o[mt][dt];
      *(u32*)(orow + dt * 16 + quad * 4) = cvtpk(v[0] * inv, v[1] * inv);
      *(u32*)(orow + dt * 16 + quad * 4 + 2) = cvtpk(v[2] * inv, v[3] * inv);
    }
  }
}

extern "C" void kernel_launch(void* const* d_in, const int* in_sizes, int n_in,
                              void* d_out, int out_size, void* d_ws, size_t ws_size,
                              hipStream_t stream) {
  const float* x  = (const float*)d_in[0];
  const float* Wq = (const float*)d_in[1];
  const float* Wk = (const float*)d_in[2];
  const float* Wv = (const float*)d_in[3];
  const float* W1 = (const float*)d_in[4];
  const float* b1 = (const float*)d_in[5];
  const float* W2 = (const float*)d_in[6];
  const float* b2 = (const float*)d_in[7];
  float* out = (float*)d_out;

  u16* ws    = (u16*)d_ws;
  u16* W1t   = ws;                             // [4096][1024]
  u16* W2t   = W1t + (size_t)4096 * 1024;      // [1024][4096]
  u16* att   = W2t + (size_t)4096 * 1024;      // [B*T][1024]  (also v_tmp)
  u16* xb    = att + (size_t)MROWS * 1024;     // [B*T][1024]
  u16* Wqkvt = xb + (size_t)MROWS * 1024;      // [3072][1024]
  u16* q     = Wqkvt + (size_t)3072 * 1024;    // [B*H][T][64]
  u16* k     = q + (size_t)MROWS * 1024;       // [B*H][T][64]
  u16* vt    = k + (size_t)MROWS * 1024;       // [B*H][64][T]
  u16* v_tmp = att;                            // [B*H][T][64]
  u16* h     = xb;                             // [B*T][4096] overlaps xb..vt

  cvt_f32_bf16<<<MROWS * 1024 / 1024, 256, 0, stream>>>(x, xb);

  dim3 tb(32, 8);
  transpose_qkv<<<dim3(2, 32, 48), tb, 0, stream>>>(Wq, Wk, Wv, Wqkvt);
  transpose_f32_bf16<<<dim3(128, 32, 1), tb, 0, stream>>>(W1, W1t, 1024, 4096, 0, 0);
  transpose_f32_bf16<<<dim3(32, 128, 1), tb, 0, stream>>>(W2, W2t, 4096, 1024, 0, 0);

  // QKV projection: [8192][1024] x [3072][1024]^T -> q/k/v (coalesced scatter)
  gemm128<0><<<768, 512, 0, stream>>>(xb, Wqkvt, nullptr, q, k, v_tmp, 3072, 1024);
  // v [BH][T][64] -> vt [BH][64][T]
  transpose_v_bf16<<<dim3(2, 64, 64), tb, 0, stream>>>(v_tmp, vt);
  // MFMA causal flash attention -> att [B*T][1024]
  attn_mfma<<<dim3(64, 16), 256, 0, stream>>>(q, k, vt, att);
  // FFN1: att @ W1 + b1 -> h (bf16)
  gemm256<1><<<512, 512, 0, stream>>>(att, W1t, b1, h, nullptr, nullptr, 4096, 1024);
  // FFN2: relu(h @ W2 + b2) -> out (fp32), 128x256 tiles = 256 wg (full chip)
  gemm128<2><<<256, 512, 0, stream>>>(h, W2t, b2, out, nullptr, nullptr, 1024, 4096);
}